// Round 1
// baseline (2371.925 us; speedup 1.0000x reference)
//
#include <hip/hip_runtime.h>
#include <hip/hip_bf16.h>
#include <math.h>

#define B_TOT 512
#define SEQ   200
#define D     128
#define DH    256
#define DFF   512
#define LPAD  256
#define PADL  56
#define NLAY  2
#define CC    16   // channels per scan block

// ---------------------------------------------------------------------------
// Setup: lambda powers (exact tree needs lambda^1..lambda^128), in-proj
// epilogue scale/bias (gamma, bias*gamma).
// ---------------------------------------------------------------------------
__global__ void setup_params_kernel(const float* __restrict__ params_log,
                                    const float* __restrict__ in_br,
                                    const float* __restrict__ in_bi,
                                    float* __restrict__ lam_pow,   // [NLAY][128][256] float2
                                    float* __restrict__ scale_in,  // [NLAY][512]
                                    float* __restrict__ bias_in)   // [NLAY][512]
{
    int li = blockIdx.x;
    int c  = threadIdx.x;             // 256 threads
    const float* pl = params_log + (size_t)li * 3 * DH;
    float nu = expf(pl[c]);
    float th = expf(pl[DH + c]);
    float ga = expf(pl[2 * DH + c]);
    float mag = expf(-nu);
    float lr = mag * cosf(th);
    float lim = mag * sinf(th);
    float2* lp = (float2*)(lam_pow + (size_t)li * 65536);
    float pr = lr, pi = lim;
    lp[c] = make_float2(pr, pi);      // lambda^1
    for (int k = 1; k < 128; ++k) {
        float nr = pr * lr - pi * lim;
        float ni = pr * lim + pi * lr;
        pr = nr; pi = ni;
        lp[(size_t)k * DH + c] = make_float2(pr, pi);
    }
    scale_in[li * 2 * DH + c]      = ga;
    scale_in[li * 2 * DH + DH + c] = ga;
    bias_in[li * 2 * DH + c]       = in_br[li * DH + c] * ga;
    bias_in[li * 2 * DH + DH + c]  = in_bi[li * DH + c] * ga;
}

// Win = [in_wr ; in_wi]  (512 x 128);  W2eff = [out_wr | -out_wi] (128 x 512)
__global__ void setup_weights_kernel(const float* __restrict__ in_wr,
                                     const float* __restrict__ in_wi,
                                     const float* __restrict__ out_wr,
                                     const float* __restrict__ out_wi,
                                     float* __restrict__ Win,
                                     float* __restrict__ W2eff)
{
    int idx = blockIdx.x * blockDim.x + threadIdx.x;   // NLAY*65536 total
    int li = idx >> 16;
    int r  = idx & 65535;

    int n = r >> 7, d = r & 127;
    float wv = (n < DH) ? in_wr[((size_t)li * DH + n) * D + d]
                        : in_wi[((size_t)li * DH + (n - DH)) * D + d];
    Win[idx] = wv;

    int dd = r >> 9, cc = r & 511;
    float w2 = (cc < DH) ? out_wr[((size_t)li * D + dd) * DH + cc]
                         : -out_wi[((size_t)li * D + dd) * DH + (cc - DH)];
    W2eff[idx] = w2;
}

// ---------------------------------------------------------------------------
// Embedding gather + LayerNorm (one wave per row of 128)
// ---------------------------------------------------------------------------
__global__ __launch_bounds__(256) void embed_ln_kernel(
    const float* __restrict__ emb, const int* __restrict__ seq,
    const float* __restrict__ g, const float* __restrict__ bt,
    float* __restrict__ x)
{
    int row  = blockIdx.x * 4 + (threadIdx.x >> 6);
    int lane = threadIdx.x & 63;
    int item = seq[row];
    float2 v = *(const float2*)(emb + (size_t)item * D + lane * 2);
    float s = v.x + v.y;
#pragma unroll
    for (int o = 32; o > 0; o >>= 1) s += __shfl_xor(s, o);
    float mu = s * (1.0f / D);
    float d0 = v.x - mu, d1 = v.y - mu;
    float vs = d0 * d0 + d1 * d1;
#pragma unroll
    for (int o = 32; o > 0; o >>= 1) vs += __shfl_xor(vs, o);
    float rstd = rsqrtf(vs * (1.0f / D) + 1e-5f);
    float2 gg = *(const float2*)(g + lane * 2);
    float2 bb = *(const float2*)(bt + lane * 2);
    float2 o2 = make_float2(d0 * rstd * gg.x + bb.x, d1 * rstd * gg.y + bb.y);
    *(float2*)(x + (size_t)row * D + lane * 2) = o2;
}

__global__ __launch_bounds__(256) void ln_kernel(
    const float* __restrict__ y, const float* __restrict__ g,
    const float* __restrict__ bt, float* __restrict__ x)
{
    int row  = blockIdx.x * 4 + (threadIdx.x >> 6);
    int lane = threadIdx.x & 63;
    float2 v = *(const float2*)(y + (size_t)row * D + lane * 2);
    float s = v.x + v.y;
#pragma unroll
    for (int o = 32; o > 0; o >>= 1) s += __shfl_xor(s, o);
    float mu = s * (1.0f / D);
    float d0 = v.x - mu, d1 = v.y - mu;
    float vs = d0 * d0 + d1 * d1;
#pragma unroll
    for (int o = 32; o > 0; o >>= 1) vs += __shfl_xor(vs, o);
    float rstd = rsqrtf(vs * (1.0f / D) + 1e-5f);
    float2 gg = *(const float2*)(g + lane * 2);
    float2 bb = *(const float2*)(bt + lane * 2);
    float2 o2 = make_float2(d0 * rstd * gg.x + bb.x, d1 * rstd * gg.y + bb.y);
    *(float2*)(x + (size_t)row * D + lane * 2) = o2;
}

// ---------------------------------------------------------------------------
// Exact replica of the reference tree scan (8 levels over 256 padded slots).
// One block: one batch element x 16 complex channels, in-place on h.
// h layout: (rows = b*200+s, cols = [re(0..255) | im(0..255)])
// ---------------------------------------------------------------------------
__global__ __launch_bounds__(256) void lru_scan_kernel(
    float* __restrict__ h,
    const float2* __restrict__ lam_pow,   // [128][256], entry k = lambda^{k+1}
    const int* __restrict__ seq)          // chunk base, (..,200)
{
    __shared__ float2 hb[LPAD][CC];   // 32 KB
    __shared__ int mk[LPAD];
    int b  = blockIdx.y;
    int c0 = blockIdx.x * CC;
    int tid = threadIdx.x;

    {   // mask for all 256 padded positions
        int t = tid;
        int m = 0;
        if (t >= PADL) m = (seq[(size_t)b * SEQ + (t - PADL)] > 0) ? 1 : 0;
        mk[t] = m;
    }
    int c  = tid & (CC - 1);
    int tl = tid >> 4;                 // 16 t-lanes
    float* base = h + (size_t)b * SEQ * (2 * DH);
    for (int t = tl; t < LPAD; t += 16) {
        float2 v = make_float2(0.f, 0.f);
        if (t >= PADL) {
            const float* row = base + (size_t)(t - PADL) * (2 * DH);
            v.x = row[c0 + c];
            v.y = row[DH + c0 + c];
        }
        hb[t][c] = v;
    }
    __syncthreads();
    for (int i = 1; i <= 8; ++i) {
        int half = 1 << (i - 1);
        for (int u = tl; u < 128; u += 16) {
            int kb  = u >> (i - 1);
            int j   = u & (half - 1);
            int src = kb * (half << 1) + half - 1;   // end of first half
            if (mk[src]) {
                int t = src + 1 + j;
                float2 s  = hb[src][c];
                float2 lp = lam_pow[(size_t)j * DH + c0 + c];  // lambda^{j+1}
                float2 dd = hb[t][c];
                dd.x += lp.x * s.x - lp.y * s.y;
                dd.y += lp.x * s.y + lp.y * s.x;
                hb[t][c] = dd;
            }
        }
        __syncthreads();
    }
    for (int t = PADL + tl; t < LPAD; t += 16) {
        float* row = base + (size_t)(t - PADL) * (2 * DH);
        float2 v = hb[t][c];
        row[c0 + c]      = v.x;
        row[DH + c0 + c] = v.y;
    }
}

// ---------------------------------------------------------------------------
// fp32 GEMM: C(M,N) = A(M,K) @ W(N,K)^T + epilogue
// MODE 0: C = acc*e0[n] + e1[n]                (in-proj: gamma scale + bias)
// MODE 1: C = acc + e0[n] + e1[m*N+n]          (bias + residual)
// MODE 2: C = gelu_exact(acc + e0[n])          (FFN1)
// BM=BN=128, BK=32, 256 threads, 8x8 per thread.
// ---------------------------------------------------------------------------
template <int MODE>
__global__ __launch_bounds__(256) void gemm_kernel(
    const float* __restrict__ A, const float* __restrict__ W,
    float* __restrict__ C, int M, int N, int K,
    const float* __restrict__ e0, const float* __restrict__ e1)
{
    __shared__ float As[32][132];
    __shared__ float Bs[32][132];
    int tid = threadIdx.x;
    int tx = tid & 15;          // n
    int ty = tid >> 4;          // m
    int m0 = blockIdx.x * 128;
    int n0 = blockIdx.y * 128;
    float acc[8][8];
#pragma unroll
    for (int i = 0; i < 8; ++i)
#pragma unroll
        for (int j = 0; j < 8; ++j) acc[i][j] = 0.f;

    for (int k0 = 0; k0 < K; k0 += 32) {
#pragma unroll
        for (int v = tid; v < 1024; v += 256) {
            int r  = v >> 3;
            int c4 = (v & 7) * 4;
            float4 fa = *(const float4*)(A + (size_t)(m0 + r) * K + k0 + c4);
            As[c4 + 0][r] = fa.x; As[c4 + 1][r] = fa.y;
            As[c4 + 2][r] = fa.z; As[c4 + 3][r] = fa.w;
            float4 fb = *(const float4*)(W + (size_t)(n0 + r) * K + k0 + c4);
            Bs[c4 + 0][r] = fb.x; Bs[c4 + 1][r] = fb.y;
            Bs[c4 + 2][r] = fb.z; Bs[c4 + 3][r] = fb.w;
        }
        __syncthreads();
#pragma unroll
        for (int k = 0; k < 32; ++k) {
            float4 a0 = *(const float4*)&As[k][ty * 8];
            float4 a1 = *(const float4*)&As[k][ty * 8 + 4];
            float4 b0 = *(const float4*)&Bs[k][tx * 8];
            float4 b1 = *(const float4*)&Bs[k][tx * 8 + 4];
            float am[8] = {a0.x, a0.y, a0.z, a0.w, a1.x, a1.y, a1.z, a1.w};
            float bn[8] = {b0.x, b0.y, b0.z, b0.w, b1.x, b1.y, b1.z, b1.w};
#pragma unroll
            for (int i = 0; i < 8; ++i)
#pragma unroll
                for (int j = 0; j < 8; ++j) acc[i][j] += am[i] * bn[j];
        }
        __syncthreads();
    }

#pragma unroll
    for (int i = 0; i < 8; ++i) {
        int m = m0 + ty * 8 + i;
#pragma unroll
        for (int hf = 0; hf < 2; ++hf) {
            int n = n0 + tx * 8 + hf * 4;
            float4 r;
            float* rp = (float*)&r;
#pragma unroll
            for (int q = 0; q < 4; ++q) {
                float val = acc[i][hf * 4 + q];
                int nn = n + q;
                if (MODE == 0) {
                    val = val * e0[nn] + e1[nn];
                } else if (MODE == 1) {
                    val = val + e0[nn] + e1[(size_t)m * N + nn];
                } else {
                    val = val + e0[nn];
                    val = 0.5f * val * (1.0f + erff(val * 0.70710678118654752f));
                }
                rp[q] = val;
            }
            *(float4*)(C + (size_t)m * N + n) = r;
        }
    }
}

// ---------------------------------------------------------------------------
__global__ void gather_kernel(const float* __restrict__ x,
                              const int* __restrict__ seqlen,
                              float* __restrict__ out, int b0, int Bc)
{
    int i = blockIdx.x * 256 + threadIdx.x;
    if (i >= Bc * D) return;
    int b = i >> 7, d = i & 127;
    int idx = seqlen[b0 + b] - 1;                 // 0..199
    out[(size_t)(b0 + b) * D + d] = x[((size_t)b * SEQ + idx) * D + d];
}

// ---------------------------------------------------------------------------
extern "C" void kernel_launch(void* const* d_in, const int* in_sizes, int n_in,
                              void* d_out, int out_size, void* d_ws, size_t ws_size,
                              hipStream_t stream)
{
    const float* token_emb  = (const float*)d_in[0];
    const float* emb_ln_g   = (const float*)d_in[1];
    const float* emb_ln_b   = (const float*)d_in[2];
    const float* params_log = (const float*)d_in[3];
    const float* in_wr      = (const float*)d_in[4];
    const float* in_wi      = (const float*)d_in[5];
    const float* in_br      = (const float*)d_in[6];
    const float* in_bi      = (const float*)d_in[7];
    const float* out_wr     = (const float*)d_in[8];
    const float* out_wi     = (const float*)d_in[9];
    const float* out_br     = (const float*)d_in[10];
    const float* lru_ln_g   = (const float*)d_in[12];
    const float* lru_ln_b   = (const float*)d_in[13];
    const float* w1         = (const float*)d_in[14];
    const float* b1         = (const float*)d_in[15];
    const float* w2         = (const float*)d_in[16];
    const float* b2         = (const float*)d_in[17];
    const float* ffn_ln_g   = (const float*)d_in[18];
    const float* ffn_ln_b   = (const float*)d_in[19];
    const int*   item_seq   = (const int*)d_in[20];
    const int*   item_seq_len = (const int*)d_in[21];
    float* out = (float*)d_out;

    float* ws       = (float*)d_ws;
    float* Win      = ws;                      // NLAY*65536
    float* W2eff    = Win + NLAY * 65536;      // NLAY*65536
    float* lam_pow  = W2eff + NLAY * 65536;    // NLAY*65536
    float* scale_in = lam_pow + NLAY * 65536;  // NLAY*512
    float* bias_in  = scale_in + NLAY * 512;   // NLAY*512
    float* bufs     = bias_in + NLAY * 512;
    size_t table_floats = (size_t)(bufs - ws);

    int Bc = B_TOT;
    while (Bc > 32) {
        size_t need = (table_floats + (size_t)Bc * SEQ * (D + DFF + D)) * sizeof(float);
        if (need <= ws_size) break;
        Bc >>= 1;
    }
    float* xbuf = bufs;
    float* hbuf = xbuf + (size_t)Bc * SEQ * D;
    float* ybuf = hbuf + (size_t)Bc * SEQ * DFF;

    setup_params_kernel<<<NLAY, 256, 0, stream>>>(params_log, in_br, in_bi,
                                                  lam_pow, scale_in, bias_in);
    setup_weights_kernel<<<NLAY * 65536 / 256, 256, 0, stream>>>(
        in_wr, in_wi, out_wr, out_wi, Win, W2eff);

    for (int b0 = 0; b0 < B_TOT; b0 += Bc) {
        int M = Bc * SEQ;
        embed_ln_kernel<<<M / 4, 256, 0, stream>>>(
            token_emb, item_seq + (size_t)b0 * SEQ, emb_ln_g, emb_ln_b, xbuf);

        for (int li = 0; li < NLAY; ++li) {
            // in-proj: h = (x @ [wr;wi]^T + b) * gamma
            gemm_kernel<0><<<dim3(M / 128, (2 * DH) / 128), 256, 0, stream>>>(
                xbuf, Win + (size_t)li * 65536, hbuf, M, 2 * DH, D,
                scale_in + li * 512, bias_in + li * 512);
            // exact tree scan (in place)
            lru_scan_kernel<<<dim3(DH / CC, Bc), 256, 0, stream>>>(
                hbuf, (const float2*)(lam_pow + (size_t)li * 65536),
                item_seq + (size_t)b0 * SEQ);
            // out-proj + residual
            gemm_kernel<1><<<dim3(M / 128, D / 128), 256, 0, stream>>>(
                hbuf, W2eff + (size_t)li * 65536, ybuf, M, D, 2 * DH,
                out_br + li * D, xbuf);
            ln_kernel<<<M / 4, 256, 0, stream>>>(ybuf, lru_ln_g + li * D,
                                                 lru_ln_b + li * D, xbuf);
            // FFN
            gemm_kernel<2><<<dim3(M / 128, DFF / 128), 256, 0, stream>>>(
                xbuf, w1 + (size_t)li * DFF * D, hbuf, M, DFF, D,
                b1 + li * DFF, (const float*)0);
            gemm_kernel<1><<<dim3(M / 128, D / 128), 256, 0, stream>>>(
                hbuf, w2 + (size_t)li * D * DFF, ybuf, M, D, DFF,
                b2 + li * D, xbuf);
            ln_kernel<<<M / 4, 256, 0, stream>>>(ybuf, ffn_ln_g + li * D,
                                                 ffn_ln_b + li * D, xbuf);
        }
        gather_kernel<<<(Bc * D + 255) / 256, 256, 0, stream>>>(
            xbuf, item_seq_len, out, b0, Bc);
    }
}

// Round 2
// 1117.230 us; speedup vs baseline: 2.1230x; 2.1230x over previous
//
#include <hip/hip_runtime.h>
#include <hip/hip_bf16.h>
#include <math.h>

#define B_TOT 512
#define SEQ   200
#define D     128
#define DH    256
#define DFF   512
#define LPAD  256
#define PADL  56
#define NLAY  2
#define CC2   32   // channels per scan block

typedef __attribute__((ext_vector_type(8))) short bf16x8;
typedef __attribute__((ext_vector_type(4))) float floatx4;

static __device__ inline float bf2f(ushort u) {
    union { unsigned int i; float f; } v; v.i = ((unsigned int)u) << 16; return v.f;
}
static __device__ inline ushort f2bf(float x) {
    union { float f; unsigned int i; } v; v.f = x;
    unsigned int r = (v.i + 0x7FFFu + ((v.i >> 16) & 1u)) >> 16;   // RNE
    return (ushort)r;
}

// ---------------------------------------------------------------------------
// lambda powers + in-proj epilogue scale/bias
// ---------------------------------------------------------------------------
__global__ void setup_params_kernel(const float* __restrict__ params_log,
                                    const float* __restrict__ in_br,
                                    const float* __restrict__ in_bi,
                                    float* __restrict__ lam_pow,   // [NLAY][128][256] float2
                                    float* __restrict__ scale_in,  // [NLAY][512]
                                    float* __restrict__ bias_in)   // [NLAY][512]
{
    int li = blockIdx.x;
    int c  = threadIdx.x;             // 256 threads
    const float* pl = params_log + (size_t)li * 3 * DH;
    float nu = expf(pl[c]);
    float th = expf(pl[DH + c]);
    float ga = expf(pl[2 * DH + c]);
    float mag = expf(-nu);
    float lr = mag * cosf(th);
    float lim = mag * sinf(th);
    float2* lp = (float2*)(lam_pow + (size_t)li * 65536);
    float pr = lr, pi = lim;
    lp[c] = make_float2(pr, pi);
    for (int k = 1; k < 128; ++k) {
        float nr = pr * lr - pi * lim;
        float ni = pr * lim + pi * lr;
        pr = nr; pi = ni;
        lp[(size_t)k * DH + c] = make_float2(pr, pi);
    }
    scale_in[li * 2 * DH + c]      = ga;
    scale_in[li * 2 * DH + DH + c] = ga;
    bias_in[li * 2 * DH + c]       = in_br[li * DH + c] * ga;
    bias_in[li * 2 * DH + DH + c]  = in_bi[li * DH + c] * ga;
}

// Win=[in_wr;in_wi] (512x128), W2eff=[out_wr|-out_wi] (128x512), w1,w2 copies — all bf16
__global__ void setup_weights_kernel(const float* __restrict__ in_wr,
                                     const float* __restrict__ in_wi,
                                     const float* __restrict__ out_wr,
                                     const float* __restrict__ out_wi,
                                     const float* __restrict__ w1,
                                     const float* __restrict__ w2,
                                     ushort* __restrict__ Winb,
                                     ushort* __restrict__ W2effb,
                                     ushort* __restrict__ w1b,
                                     ushort* __restrict__ w2b)
{
    int idx = blockIdx.x * blockDim.x + threadIdx.x;   // NLAY*65536
    int li = idx >> 16;
    int r  = idx & 65535;

    int n = r >> 7, d = r & 127;
    float wv = (n < DH) ? in_wr[((size_t)li * DH + n) * D + d]
                        : in_wi[((size_t)li * DH + (n - DH)) * D + d];
    Winb[idx] = f2bf(wv);

    int dd = r >> 9, cc = r & 511;
    float w2v = (cc < DH) ? out_wr[((size_t)li * D + dd) * DH + cc]
                          : -out_wi[((size_t)li * D + dd) * DH + (cc - DH)];
    W2effb[idx] = f2bf(w2v);

    w1b[idx] = f2bf(w1[idx]);
    w2b[idx] = f2bf(w2[idx]);
}

// ---------------------------------------------------------------------------
// Embedding gather + LayerNorm -> bf16 x
// ---------------------------------------------------------------------------
__global__ __launch_bounds__(256) void embed_ln_kernel(
    const float* __restrict__ emb, const int* __restrict__ seq,
    const float* __restrict__ g, const float* __restrict__ bt,
    ushort* __restrict__ x)
{
    int row  = blockIdx.x * 4 + (threadIdx.x >> 6);
    int lane = threadIdx.x & 63;
    int item = seq[row];
    float2 v = *(const float2*)(emb + (size_t)item * D + lane * 2);
    float s = v.x + v.y;
#pragma unroll
    for (int o = 32; o > 0; o >>= 1) s += __shfl_xor(s, o);
    float mu = s * (1.0f / D);
    float d0 = v.x - mu, d1 = v.y - mu;
    float vs = d0 * d0 + d1 * d1;
#pragma unroll
    for (int o = 32; o > 0; o >>= 1) vs += __shfl_xor(vs, o);
    float rstd = rsqrtf(vs * (1.0f / D) + 1e-5f);
    float2 gg = *(const float2*)(g + lane * 2);
    float2 bb = *(const float2*)(bt + lane * 2);
    ushort2 o2;
    o2.x = f2bf(d0 * rstd * gg.x + bb.x);
    o2.y = f2bf(d1 * rstd * gg.y + bb.y);
    *(ushort2*)(x + (size_t)row * D + lane * 2) = o2;
}

// LayerNorm: fp32 y in, bf16 (or fp32 for final) out
template <bool BF16OUT>
__global__ __launch_bounds__(256) void ln_kernel(
    const float* __restrict__ y, const float* __restrict__ g,
    const float* __restrict__ bt, void* __restrict__ xout)
{
    int row  = blockIdx.x * 4 + (threadIdx.x >> 6);
    int lane = threadIdx.x & 63;
    float2 v = *(const float2*)(y + (size_t)row * D + lane * 2);
    float s = v.x + v.y;
#pragma unroll
    for (int o = 32; o > 0; o >>= 1) s += __shfl_xor(s, o);
    float mu = s * (1.0f / D);
    float d0 = v.x - mu, d1 = v.y - mu;
    float vs = d0 * d0 + d1 * d1;
#pragma unroll
    for (int o = 32; o > 0; o >>= 1) vs += __shfl_xor(vs, o);
    float rstd = rsqrtf(vs * (1.0f / D) + 1e-5f);
    float2 gg = *(const float2*)(g + lane * 2);
    float2 bb = *(const float2*)(bt + lane * 2);
    float r0 = d0 * rstd * gg.x + bb.x;
    float r1 = d1 * rstd * gg.y + bb.y;
    if (BF16OUT) {
        ushort2 o2; o2.x = f2bf(r0); o2.y = f2bf(r1);
        *(ushort2*)((ushort*)xout + (size_t)row * D + lane * 2) = o2;
    } else {
        *(float2*)((float*)xout + (size_t)row * D + lane * 2) = make_float2(r0, r1);
    }
}

// ---------------------------------------------------------------------------
// Exact tree scan, bf16 h in/out, fp32 LDS compute.
// One block: one batch element x 32 complex channels.
// ---------------------------------------------------------------------------
__global__ __launch_bounds__(256) void lru_scan_kernel(
    ushort* __restrict__ h,
    const float2* __restrict__ lam_pow,   // [128][256], entry k = lambda^{k+1}
    const int* __restrict__ seq)
{
    __shared__ float hR[LPAD][CC2];   // 32 KB
    __shared__ float hI[LPAD][CC2];   // 32 KB
    __shared__ int mk[LPAD];
    int b  = blockIdx.y;
    int c0 = blockIdx.x * CC2;
    int tid = threadIdx.x;

    {
        int t = tid;
        int m = 0;
        if (t >= PADL) m = (seq[(size_t)b * SEQ + (t - PADL)] > 0) ? 1 : 0;
        mk[t] = m;
    }
    int c  = tid & (CC2 - 1);
    int tl = tid >> 5;                 // 8 t-lanes
    ushort* base = h + (size_t)b * SEQ * (2 * DH);
    for (int t = tl; t < LPAD; t += 8) {
        float vr = 0.f, vi = 0.f;
        if (t >= PADL) {
            const ushort* row = base + (size_t)(t - PADL) * (2 * DH);
            vr = bf2f(row[c0 + c]);
            vi = bf2f(row[DH + c0 + c]);
        }
        hR[t][c] = vr; hI[t][c] = vi;
    }
    __syncthreads();
    for (int i = 1; i <= 8; ++i) {
        int half = 1 << (i - 1);
        for (int u = tl; u < 128; u += 8) {
            int kb  = u >> (i - 1);
            int j   = u & (half - 1);
            int src = kb * (half << 1) + half - 1;
            if (mk[src]) {
                int t = src + 1 + j;
                float sr = hR[src][c], si = hI[src][c];
                float2 lp = lam_pow[(size_t)j * DH + c0 + c];  // lambda^{j+1}
                hR[t][c] += lp.x * sr - lp.y * si;
                hI[t][c] += lp.x * si + lp.y * sr;
            }
        }
        __syncthreads();
    }
    for (int t = PADL + tl; t < LPAD; t += 8) {
        ushort* row = base + (size_t)(t - PADL) * (2 * DH);
        row[c0 + c]      = f2bf(hR[t][c]);
        row[DH + c0 + c] = f2bf(hI[t][c]);
    }
}

// ---------------------------------------------------------------------------
// bf16 MFMA GEMM: C(M,N) = A(M,K) @ W(N,K)^T + epilogue
// MODE 0: bf16 C = acc*e0[n] + e1[n]                 (in-proj)
// MODE 1: fp32 C = acc + e0[n] + bf2f(res[m*128+n])  (bias + residual)
// MODE 2: bf16 C = gelu_exact(acc + e0[n])           (FFN1)
// 128x128 tile, BK=64, 256 threads (4 waves, each 64x64 via 4x4 MFMA tiles).
// XOR-swizzled LDS (16B chunk c ^= row&7): uniform bank-group spread for
// both ds_write_b128 staging and ds_read_b128 fragment reads.
// ---------------------------------------------------------------------------
template <int MODE>
__global__ __launch_bounds__(256) void gemm_bf16_kernel(
    const ushort* __restrict__ A, const ushort* __restrict__ W,
    void* __restrict__ Cout, int M, int N, int K,
    const float* __restrict__ e0, const float* __restrict__ e1,
    const ushort* __restrict__ res)
{
    __shared__ char As[16384];   // 128 rows x 64 bf16 (8 chunks of 16B, swizzled)
    __shared__ char Bs[16384];
    int tid = threadIdx.x;
    int l = tid & 63, w = tid >> 6;
    int wm = w >> 1, wn = w & 1;
    int lr = l & 15, lq = l >> 4;
    int m0 = blockIdx.x * 128, n0 = blockIdx.y * 128;

    floatx4 acc[4][4];
#pragma unroll
    for (int i = 0; i < 4; ++i)
#pragma unroll
        for (int j = 0; j < 4; ++j) acc[i][j] = (floatx4)0.f;

    for (int k0 = 0; k0 < K; k0 += 64) {
#pragma unroll
        for (int it = 0; it < 4; ++it) {
            int instr = w * 4 + it;          // 0..15
            int g  = instr >> 1;
            int hh = instr & 1;
            int r = g * 16 + lr;             // tile row
            int c = hh * 4 + lq;             // 16B chunk 0..7
            float4 va = *(const float4*)(A + (size_t)(m0 + r) * K + k0 + c * 8);
            *(float4*)(As + r * 128 + ((c ^ (r & 7)) * 16)) = va;
            float4 vb = *(const float4*)(W + (size_t)(n0 + r) * K + k0 + c * 8);
            *(float4*)(Bs + r * 128 + ((c ^ (r & 7)) * 16)) = vb;
        }
        __syncthreads();
#pragma unroll
        for (int kk = 0; kk < 2; ++kk) {
            bf16x8 af[4], bfr[4];
#pragma unroll
            for (int i = 0; i < 4; ++i) {
                int ra = wm * 64 + i * 16 + lr;
                int ca = kk * 4 + lq;
                af[i] = *(const bf16x8*)(As + ra * 128 + ((ca ^ (ra & 7)) * 16));
                int rb = wn * 64 + i * 16 + lr;
                bfr[i] = *(const bf16x8*)(Bs + rb * 128 + ((ca ^ (rb & 7)) * 16));
            }
#pragma unroll
            for (int i = 0; i < 4; ++i)
#pragma unroll
                for (int j = 0; j < 4; ++j)
                    acc[i][j] = __builtin_amdgcn_mfma_f32_16x16x32_bf16(
                        af[i], bfr[j], acc[i][j], 0, 0, 0);
        }
        __syncthreads();
    }

    // epilogue: tile (i,j): col = n0+wn*64+j*16+lr; row = m0+wm*64+i*16+lq*4+reg
#pragma unroll
    for (int i = 0; i < 4; ++i) {
#pragma unroll
        for (int reg = 0; reg < 4; ++reg) {
            int row = m0 + wm * 64 + i * 16 + lq * 4 + reg;
#pragma unroll
            for (int j = 0; j < 4; ++j) {
                int col = n0 + wn * 64 + j * 16 + lr;
                float val = acc[i][j][reg];
                if (MODE == 0) {
                    val = val * e0[col] + e1[col];
                    ((ushort*)Cout)[(size_t)row * N + col] = f2bf(val);
                } else if (MODE == 1) {
                    val = val + e0[col] + bf2f(res[(size_t)row * D + col]);
                    ((float*)Cout)[(size_t)row * N + col] = val;
                } else {
                    val = val + e0[col];
                    val = 0.5f * val * (1.0f + erff(val * 0.70710678118654752f));
                    ((ushort*)Cout)[(size_t)row * N + col] = f2bf(val);
                }
            }
        }
    }
}

// ---------------------------------------------------------------------------
__global__ void gather_kernel(const float* __restrict__ x,
                              const int* __restrict__ seqlen,
                              float* __restrict__ out, int b0, int Bc)
{
    int i = blockIdx.x * 256 + threadIdx.x;
    if (i >= Bc * D) return;
    int b = i >> 7, d = i & 127;
    int idx = seqlen[b0 + b] - 1;
    out[(size_t)(b0 + b) * D + d] = x[((size_t)b * SEQ + idx) * D + d];
}

// ---------------------------------------------------------------------------
extern "C" void kernel_launch(void* const* d_in, const int* in_sizes, int n_in,
                              void* d_out, int out_size, void* d_ws, size_t ws_size,
                              hipStream_t stream)
{
    const float* token_emb  = (const float*)d_in[0];
    const float* emb_ln_g   = (const float*)d_in[1];
    const float* emb_ln_b   = (const float*)d_in[2];
    const float* params_log = (const float*)d_in[3];
    const float* in_wr      = (const float*)d_in[4];
    const float* in_wi      = (const float*)d_in[5];
    const float* in_br      = (const float*)d_in[6];
    const float* in_bi      = (const float*)d_in[7];
    const float* out_wr     = (const float*)d_in[8];
    const float* out_wi     = (const float*)d_in[9];
    const float* out_br     = (const float*)d_in[10];
    const float* lru_ln_g   = (const float*)d_in[12];
    const float* lru_ln_b   = (const float*)d_in[13];
    const float* w1         = (const float*)d_in[14];
    const float* b1         = (const float*)d_in[15];
    const float* w2         = (const float*)d_in[16];
    const float* b2         = (const float*)d_in[17];
    const float* ffn_ln_g   = (const float*)d_in[18];
    const float* ffn_ln_b   = (const float*)d_in[19];
    const int*   item_seq   = (const int*)d_in[20];
    const int*   item_seq_len = (const int*)d_in[21];
    float* out = (float*)d_out;

    char* ws = (char*)d_ws;
    ushort* Winb   = (ushort*)ws;                      ws += NLAY * 65536 * 2;
    ushort* W2effb = (ushort*)ws;                      ws += NLAY * 65536 * 2;
    ushort* w1b    = (ushort*)ws;                      ws += NLAY * 65536 * 2;
    ushort* w2b    = (ushort*)ws;                      ws += NLAY * 65536 * 2;
    float* lam_pow = (float*)ws;                       ws += NLAY * 65536 * 4;
    float* scale_in = (float*)ws;                      ws += NLAY * 512 * 4;
    float* bias_in  = (float*)ws;                      ws += NLAY * 512 * 4;
    size_t table_bytes = (size_t)(ws - (char*)d_ws);

    int Bc = B_TOT;
    while (Bc > 32) {
        size_t need = table_bytes + (size_t)Bc * SEQ * (D * 2 + 2 * DH * 2 + D * 4) + 1024;
        if (need <= ws_size) break;
        Bc >>= 1;
    }
    ushort* xb = (ushort*)ws;                          ws += (size_t)Bc * SEQ * D * 2;
    ushort* hb = (ushort*)ws;                          ws += (size_t)Bc * SEQ * 2 * DH * 2;
    float*  yb = (float*)ws;
    float*  xfin = (float*)hb;   // reuse h buffer for final fp32 x

    setup_params_kernel<<<NLAY, 256, 0, stream>>>(params_log, in_br, in_bi,
                                                  lam_pow, scale_in, bias_in);
    setup_weights_kernel<<<NLAY * 65536 / 256, 256, 0, stream>>>(
        in_wr, in_wi, out_wr, out_wi, w1, w2, Winb, W2effb, w1b, w2b);

    for (int b0 = 0; b0 < B_TOT; b0 += Bc) {
        int M = Bc * SEQ;
        embed_ln_kernel<<<M / 4, 256, 0, stream>>>(
            token_emb, item_seq + (size_t)b0 * SEQ, emb_ln_g, emb_ln_b, xb);

        for (int li = 0; li < NLAY; ++li) {
            // in-proj: h = (x @ [wr;wi]^T)*gamma + b*gamma   -> bf16 h
            gemm_bf16_kernel<0><<<dim3(M / 128, (2 * DH) / 128), 256, 0, stream>>>(
                xb, Winb + (size_t)li * 65536, hb, M, 2 * DH, D,
                scale_in + li * 512, bias_in + li * 512, (const ushort*)0);
            // exact tree scan (in place, bf16)
            lru_scan_kernel<<<dim3((2 * DH) / (2 * CC2), Bc), 256, 0, stream>>>(
                hb, (const float2*)(lam_pow + (size_t)li * 65536),
                item_seq + (size_t)b0 * SEQ);
            // out-proj + bias + residual -> fp32 y
            gemm_bf16_kernel<1><<<dim3(M / 128, D / 128), 256, 0, stream>>>(
                hb, W2effb + (size_t)li * 65536, yb, M, D, 2 * DH,
                out_br + li * D, (const float*)0, xb);
            ln_kernel<true><<<M / 4, 256, 0, stream>>>(yb, lru_ln_g + li * D,
                                                       lru_ln_b + li * D, xb);
            // FFN1 + gelu -> bf16 h
            gemm_bf16_kernel<2><<<dim3(M / 128, DFF / 128), 256, 0, stream>>>(
                xb, w1b + (size_t)li * DFF * D, hb, M, DFF, D,
                b1 + li * DFF, (const float*)0, (const ushort*)0);
            // FFN2 + bias + residual -> fp32 y
            gemm_bf16_kernel<1><<<dim3(M / 128, D / 128), 256, 0, stream>>>(
                hb, w2b + (size_t)li * D * DFF, yb, M, D, DFF,
                b2 + li * D, (const float*)0, xb);
            if (li == NLAY - 1) {
                ln_kernel<false><<<M / 4, 256, 0, stream>>>(
                    yb, ffn_ln_g + li * D, ffn_ln_b + li * D, xfin);
            } else {
                ln_kernel<true><<<M / 4, 256, 0, stream>>>(
                    yb, ffn_ln_g + li * D, ffn_ln_b + li * D, xb);
            }
        }
        gather_kernel<<<(Bc * D + 255) / 256, 256, 0, stream>>>(
            xfin, item_seq_len, out, b0, Bc);
    }
}

// Round 3
// 962.875 us; speedup vs baseline: 2.4634x; 1.1603x over previous
//
#include <hip/hip_runtime.h>
#include <hip/hip_bf16.h>
#include <math.h>

#define B_TOT 512
#define SEQ   200
#define D     128
#define DH    256
#define DFF   512
#define LPAD  256
#define PADL  56
#define NLAY  2

typedef __attribute__((ext_vector_type(8))) short bf16x8;
typedef __attribute__((ext_vector_type(4))) float floatx4;

static __device__ inline float bf2f(ushort u) {
    union { unsigned int i; float f; } v; v.i = ((unsigned int)u) << 16; return v.f;
}
static __device__ inline ushort f2bf(float x) {
    union { float f; unsigned int i; } v; v.f = x;
    unsigned int r = (v.i + 0x7FFFu + ((v.i >> 16) & 1u)) >> 16;   // RNE
    return (ushort)r;
}

// H layout: [b][g(8)][p(re/im)][s(200)][32 ch] bf16. index helper (k in 0..511,
// k<256 = re channel k, k>=256 = im channel k-256)
static __device__ inline size_t haddr(int b, int s, int k) {
    int p  = k >> 8;
    int ch = k & 255;
    int g  = ch >> 5;
    int cl = ch & 31;
    return (((((size_t)b * 8 + g) * 2 + p) * SEQ + s) * 32 + cl);
}

// ---------------------------------------------------------------------------
// lambda powers + in-proj epilogue scale/bias
// ---------------------------------------------------------------------------
__global__ void setup_params_kernel(const float* __restrict__ params_log,
                                    const float* __restrict__ in_br,
                                    const float* __restrict__ in_bi,
                                    float* __restrict__ lam_pow,   // [NLAY][128][256] float2
                                    float* __restrict__ scale_in,  // [NLAY][512]
                                    float* __restrict__ bias_in)   // [NLAY][512]
{
    int li = blockIdx.x;
    int c  = threadIdx.x;             // 256 threads
    const float* pl = params_log + (size_t)li * 3 * DH;
    float nu = expf(pl[c]);
    float th = expf(pl[DH + c]);
    float ga = expf(pl[2 * DH + c]);
    float mag = expf(-nu);
    float lr = mag * cosf(th);
    float lim = mag * sinf(th);
    float2* lp = (float2*)(lam_pow + (size_t)li * 65536);
    float pr = lr, pi = lim;
    lp[c] = make_float2(pr, pi);
    for (int k = 1; k < 128; ++k) {
        float nr = pr * lr - pi * lim;
        float ni = pr * lim + pi * lr;
        pr = nr; pi = ni;
        lp[(size_t)k * DH + c] = make_float2(pr, pi);
    }
    scale_in[li * 2 * DH + c]      = ga;
    scale_in[li * 2 * DH + DH + c] = ga;
    bias_in[li * 2 * DH + c]       = in_br[li * DH + c] * ga;
    bias_in[li * 2 * DH + DH + c]  = in_bi[li * DH + c] * ga;
}

__global__ void setup_weights_kernel(const float* __restrict__ in_wr,
                                     const float* __restrict__ in_wi,
                                     const float* __restrict__ out_wr,
                                     const float* __restrict__ out_wi,
                                     const float* __restrict__ w1,
                                     const float* __restrict__ w2,
                                     ushort* __restrict__ Winb,
                                     ushort* __restrict__ W2effb,
                                     ushort* __restrict__ w1b,
                                     ushort* __restrict__ w2b)
{
    int idx = blockIdx.x * blockDim.x + threadIdx.x;   // NLAY*65536
    int li = idx >> 16;
    int r  = idx & 65535;

    int n = r >> 7, d = r & 127;
    float wv = (n < DH) ? in_wr[((size_t)li * DH + n) * D + d]
                        : in_wi[((size_t)li * DH + (n - DH)) * D + d];
    Winb[idx] = f2bf(wv);

    int dd = r >> 9, cc = r & 511;
    float w2v = (cc < DH) ? out_wr[((size_t)li * D + dd) * DH + cc]
                          : -out_wi[((size_t)li * D + dd) * DH + (cc - DH)];
    W2effb[idx] = f2bf(w2v);

    w1b[idx] = f2bf(w1[idx]);
    w2b[idx] = f2bf(w2[idx]);
}

// ---------------------------------------------------------------------------
// Embedding gather + LayerNorm -> bf16 x
// ---------------------------------------------------------------------------
__global__ __launch_bounds__(256) void embed_ln_kernel(
    const float* __restrict__ emb, const int* __restrict__ seq,
    const float* __restrict__ g, const float* __restrict__ bt,
    ushort* __restrict__ x)
{
    int row  = blockIdx.x * 4 + (threadIdx.x >> 6);
    int lane = threadIdx.x & 63;
    int item = seq[row];
    float2 v = *(const float2*)(emb + (size_t)item * D + lane * 2);
    float s = v.x + v.y;
#pragma unroll
    for (int o = 32; o > 0; o >>= 1) s += __shfl_xor(s, o);
    float mu = s * (1.0f / D);
    float d0 = v.x - mu, d1 = v.y - mu;
    float vs = d0 * d0 + d1 * d1;
#pragma unroll
    for (int o = 32; o > 0; o >>= 1) vs += __shfl_xor(vs, o);
    float rstd = rsqrtf(vs * (1.0f / D) + 1e-5f);
    float2 gg = *(const float2*)(g + lane * 2);
    float2 bb = *(const float2*)(bt + lane * 2);
    ushort2 o2;
    o2.x = f2bf(d0 * rstd * gg.x + bb.x);
    o2.y = f2bf(d1 * rstd * gg.y + bb.y);
    *(ushort2*)(x + (size_t)row * D + lane * 2) = o2;
}

// ---------------------------------------------------------------------------
// Exact tree scan on H layout. Block = (g, b): 32 complex channels of one
// batch element; fully-contiguous 25.6 KB global span, 16B/lane accesses.
// ---------------------------------------------------------------------------
__global__ __launch_bounds__(256) void lru_scan_kernel(
    ushort* __restrict__ H,
    const float2* __restrict__ lam_pow,   // [128][256], entry k = lambda^{k+1}
    const int* __restrict__ seq)
{
    __shared__ float hR[LPAD][32];   // 32 KB
    __shared__ float hI[LPAD][32];   // 32 KB
    __shared__ int mk[LPAD];
    int g = blockIdx.x;
    int b = blockIdx.y;
    int tid = threadIdx.x;

    {   // mask
        int t = tid;
        int m = 0;
        if (t >= PADL) m = (seq[(size_t)b * SEQ + (t - PADL)] > 0) ? 1 : 0;
        mk[t] = m;
    }
    // zero pad rows
    for (int idx = tid; idx < PADL * 32; idx += 256) {
        int t = idx >> 5, c = idx & 31;
        hR[t][c] = 0.f; hI[t][c] = 0.f;
    }
    // load 12800 ushorts (2 x 200 x 32), 16B per lane, coalesced
    ushort* base = H + (size_t)(b * 8 + g) * 2 * SEQ * 32;
#pragma unroll
    for (int iter = 0; iter < 7; ++iter) {
        int idx8 = (iter * 256 + tid) * 8;
        if (idx8 < 2 * SEQ * 32) {
            uint4 raw = *(const uint4*)(base + idx8);
            int p  = idx8 >= SEQ * 32;
            int s  = (idx8 - p * SEQ * 32) >> 5;
            int cl = idx8 & 31;
            int t  = s + PADL;
            int cs = cl ^ ((t & 3) * 8);
            float* dst = (p ? &hI[0][0] : &hR[0][0]) + t * 32 + cs;
            unsigned int u[4] = {raw.x, raw.y, raw.z, raw.w};
            float4 f0, f1;
            f0.x = bf2f((ushort)(u[0] & 0xffff)); f0.y = bf2f((ushort)(u[0] >> 16));
            f0.z = bf2f((ushort)(u[1] & 0xffff)); f0.w = bf2f((ushort)(u[1] >> 16));
            f1.x = bf2f((ushort)(u[2] & 0xffff)); f1.y = bf2f((ushort)(u[2] >> 16));
            f1.z = bf2f((ushort)(u[3] & 0xffff)); f1.w = bf2f((ushort)(u[3] >> 16));
            *(float4*)(dst)     = f0;
            *(float4*)(dst + 4) = f1;
        }
    }
    __syncthreads();

    int c  = tid & 31;
    int tl = tid >> 5;                 // 8 groups
    const float2* lamg = lam_pow + g * 32 + c;
    for (int i = 1; i <= 8; ++i) {
        int half = 1 << (i - 1);
        for (int u = tl; u < 128; u += 8) {
            int kb  = u >> (i - 1);
            int j   = u & (half - 1);
            int src = kb * (half << 1) + half - 1;
            if (mk[src]) {
                int t = src + 1 + j;
                int cs_s = c ^ ((src & 3) * 8);
                int cs_t = c ^ ((t & 3) * 8);
                float sr = hR[src][cs_s], si = hI[src][cs_s];
                float2 lp = lamg[(size_t)j * DH];
                hR[t][cs_t] += lp.x * sr - lp.y * si;
                hI[t][cs_t] += lp.x * si + lp.y * sr;
            }
        }
        __syncthreads();
    }

    // store back
#pragma unroll
    for (int iter = 0; iter < 7; ++iter) {
        int idx8 = (iter * 256 + tid) * 8;
        if (idx8 < 2 * SEQ * 32) {
            int p  = idx8 >= SEQ * 32;
            int s  = (idx8 - p * SEQ * 32) >> 5;
            int cl = idx8 & 31;
            int t  = s + PADL;
            int cs = cl ^ ((t & 3) * 8);
            const float* src = (p ? &hI[0][0] : &hR[0][0]) + t * 32 + cs;
            float4 f0 = *(const float4*)(src);
            float4 f1 = *(const float4*)(src + 4);
            uint4 raw;
            raw.x = (unsigned int)f2bf(f0.x) | ((unsigned int)f2bf(f0.y) << 16);
            raw.y = (unsigned int)f2bf(f0.z) | ((unsigned int)f2bf(f0.w) << 16);
            raw.z = (unsigned int)f2bf(f1.x) | ((unsigned int)f2bf(f1.y) << 16);
            raw.w = (unsigned int)f2bf(f1.z) | ((unsigned int)f2bf(f1.w) << 16);
            *(uint4*)(base + idx8) = raw;
        }
    }
}

// ---------------------------------------------------------------------------
// bf16 MFMA GEMM, weights in A-slot / activations in B-slot:
//   D[channel][actrow] -> thread holds 4 consecutive channels per reg group.
// C(M,N) = act(M,K) @ W(N,K)^T + epilogue
// MODE 0: bf16 H-layout out = acc*e0[n] + e1[n]          (in-proj)
// MODE 1: bf16 out = LayerNorm(acc + e0[n] + res[m][n])  (out-proj / FFN2, N=128)
// MODE 2: bf16 out = gelu_exact(acc + e0[n])             (FFN1)
// AHL: activation operand read from H layout (out-proj).
// ---------------------------------------------------------------------------
template <int MODE, bool AHL>
__global__ __launch_bounds__(256) void gemm_bf16_kernel(
    const ushort* __restrict__ A, const ushort* __restrict__ W,
    ushort* __restrict__ Cout, int M, int N, int K,
    const float* __restrict__ e0, const float* __restrict__ e1,
    const ushort* __restrict__ res,
    const float* __restrict__ lng, const float* __restrict__ lnb)
{
    __shared__ char As[16384];   // 128 rows x 64 bf16, swizzled 16B chunks
    __shared__ char Bs[16384];
    __shared__ float2 lnS[2][128];
    int tid = threadIdx.x;
    int l = tid & 63, w = tid >> 6;
    int chh = w >> 1;        // channel half (0/1)
    int rh  = w & 1;         // act-row half (0/1)
    int lr = l & 15, lq = l >> 4;
    int m0 = blockIdx.x * 128, n0 = blockIdx.y * 128;

    // staged rows for this thread (2 distinct rows, each staged twice)
    int r_even = (2 * w) * 16 + lr;        // it 0,1
    int r_odd  = (2 * w + 1) * 16 + lr;    // it 2,3
    int sbE = 0, ssE = 0, sbO = 0, ssO = 0;
    if (AHL) {
        unsigned int ge = m0 + r_even, go = m0 + r_odd;
        sbE = ge / SEQ; ssE = ge - sbE * SEQ;
        sbO = go / SEQ; ssO = go - sbO * SEQ;
    }

    floatx4 acc[4][4];
#pragma unroll
    for (int i = 0; i < 4; ++i)
#pragma unroll
        for (int j = 0; j < 4; ++j) acc[i][j] = (floatx4)0.f;

    for (int k0 = 0; k0 < K; k0 += 64) {
#pragma unroll
        for (int it = 0; it < 4; ++it) {
            int r = (it < 2) ? r_even : r_odd;
            int c = (it & 1) * 4 + lq;       // 16B chunk 0..7
            uint4 va;
            if (AHL) {
                int sb = (it < 2) ? sbE : sbO;
                int ss = (it < 2) ? ssE : ssO;
                va = *(const uint4*)(A + haddr(sb, ss, k0 + c * 8));
            } else {
                va = *(const uint4*)(A + (size_t)(m0 + r) * K + k0 + c * 8);
            }
            *(uint4*)(As + r * 128 + ((c ^ (r & 7)) * 16)) = va;
            uint4 vb = *(const uint4*)(W + (size_t)(n0 + r) * K + k0 + c * 8);
            *(uint4*)(Bs + r * 128 + ((c ^ (r & 7)) * 16)) = vb;
        }
        __syncthreads();
#pragma unroll
        for (int kk = 0; kk < 2; ++kk) {
            bf16x8 wf[4], af[4];
            int ca = kk * 4 + lq;
#pragma unroll
            for (int i = 0; i < 4; ++i) {
                int rb = chh * 64 + i * 16 + lr;
                wf[i] = *(const bf16x8*)(Bs + rb * 128 + ((ca ^ (rb & 7)) * 16));
                int ra = rh * 64 + i * 16 + lr;
                af[i] = *(const bf16x8*)(As + ra * 128 + ((ca ^ (ra & 7)) * 16));
            }
#pragma unroll
            for (int i = 0; i < 4; ++i)
#pragma unroll
                for (int j = 0; j < 4; ++j)
                    acc[i][j] = __builtin_amdgcn_mfma_f32_16x16x32_bf16(
                        wf[i], af[j], acc[i][j], 0, 0, 0);
        }
        __syncthreads();
    }

    // channel = n0 + chh*64 + i*16 + lq*4 + reg ; actrow = m0 + rh*64 + j*16 + lr
    int chb[4], arow[4];
#pragma unroll
    for (int i = 0; i < 4; ++i) chb[i] = n0 + chh * 64 + i * 16 + lq * 4;
#pragma unroll
    for (int j = 0; j < 4; ++j) arow[j] = m0 + rh * 64 + j * 16 + lr;

    if (MODE == 1) {
        float4 bias[4], gv[4], bv[4];
#pragma unroll
        for (int i = 0; i < 4; ++i) {
            bias[i] = *(const float4*)(e0 + chb[i]);
            gv[i]   = *(const float4*)(lng + chb[i]);
            bv[i]   = *(const float4*)(lnb + chb[i]);
        }
        // add bias + residual
#pragma unroll
        for (int j = 0; j < 4; ++j) {
#pragma unroll
            for (int i = 0; i < 4; ++i) {
                ushort4 r4 = *(const ushort4*)(res + (size_t)arow[j] * 128 + chb[i]);
                acc[i][j][0] += ((const float*)&bias[i])[0] + bf2f(r4.x);
                acc[i][j][1] += ((const float*)&bias[i])[1] + bf2f(r4.y);
                acc[i][j][2] += ((const float*)&bias[i])[2] + bf2f(r4.z);
                acc[i][j][3] += ((const float*)&bias[i])[3] + bf2f(r4.w);
            }
        }
        // stats: per actrow sum over this wave's 64 channels
#pragma unroll
        for (int j = 0; j < 4; ++j) {
            float s = 0.f, q = 0.f;
#pragma unroll
            for (int i = 0; i < 4; ++i)
#pragma unroll
                for (int reg = 0; reg < 4; ++reg) {
                    float v = acc[i][j][reg];
                    s += v; q += v * v;
                }
            s += __shfl_xor(s, 16); q += __shfl_xor(q, 16);
            s += __shfl_xor(s, 32); q += __shfl_xor(q, 32);
            if (lq == 0) lnS[chh][rh * 64 + j * 16 + lr] = make_float2(s, q);
        }
        __syncthreads();
#pragma unroll
        for (int j = 0; j < 4; ++j) {
            int rl = rh * 64 + j * 16 + lr;
            float2 s0 = lnS[0][rl], s1 = lnS[1][rl];
            float mu  = (s0.x + s1.x) * (1.0f / 128.0f);
            float var = (s0.y + s1.y) * (1.0f / 128.0f) - mu * mu;
            float rstd = rsqrtf(var + 1e-5f);
#pragma unroll
            for (int i = 0; i < 4; ++i) {
                ushort4 u4;
                u4.x = f2bf((acc[i][j][0] - mu) * rstd * ((const float*)&gv[i])[0] + ((const float*)&bv[i])[0]);
                u4.y = f2bf((acc[i][j][1] - mu) * rstd * ((const float*)&gv[i])[1] + ((const float*)&bv[i])[1]);
                u4.z = f2bf((acc[i][j][2] - mu) * rstd * ((const float*)&gv[i])[2] + ((const float*)&bv[i])[2]);
                u4.w = f2bf((acc[i][j][3] - mu) * rstd * ((const float*)&gv[i])[3] + ((const float*)&bv[i])[3]);
                *(ushort4*)(Cout + (size_t)arow[j] * 128 + chb[i]) = u4;
            }
        }
    } else if (MODE == 0) {
        float4 sc[4], bi[4];
#pragma unroll
        for (int i = 0; i < 4; ++i) {
            sc[i] = *(const float4*)(e0 + chb[i]);
            bi[i] = *(const float4*)(e1 + chb[i]);
        }
#pragma unroll
        for (int j = 0; j < 4; ++j) {
            unsigned int gr = arow[j];
            int b = gr / SEQ, s = gr - b * SEQ;
#pragma unroll
            for (int i = 0; i < 4; ++i) {
                ushort4 u4;
                u4.x = f2bf(acc[i][j][0] * ((const float*)&sc[i])[0] + ((const float*)&bi[i])[0]);
                u4.y = f2bf(acc[i][j][1] * ((const float*)&sc[i])[1] + ((const float*)&bi[i])[1]);
                u4.z = f2bf(acc[i][j][2] * ((const float*)&sc[i])[2] + ((const float*)&bi[i])[2]);
                u4.w = f2bf(acc[i][j][3] * ((const float*)&sc[i])[3] + ((const float*)&bi[i])[3]);
                *(ushort4*)(Cout + haddr(b, s, chb[i])) = u4;
            }
        }
    } else {   // MODE 2: gelu, plain layout
#pragma unroll
        for (int i = 0; i < 4; ++i) {
            float4 bi = *(const float4*)(e0 + chb[i]);
#pragma unroll
            for (int j = 0; j < 4; ++j) {
                ushort4 u4;
                float v;
                v = acc[i][j][0] + bi.x; u4.x = f2bf(0.5f * v * (1.0f + erff(v * 0.70710678118654752f)));
                v = acc[i][j][1] + bi.y; u4.y = f2bf(0.5f * v * (1.0f + erff(v * 0.70710678118654752f)));
                v = acc[i][j][2] + bi.z; u4.z = f2bf(0.5f * v * (1.0f + erff(v * 0.70710678118654752f)));
                v = acc[i][j][3] + bi.w; u4.w = f2bf(0.5f * v * (1.0f + erff(v * 0.70710678118654752f)));
                *(ushort4*)(Cout + (size_t)arow[j] * N + chb[i]) = u4;
            }
        }
    }
}

// ---------------------------------------------------------------------------
__global__ void gather_kernel(const ushort* __restrict__ x,
                              const int* __restrict__ seqlen,
                              float* __restrict__ out, int b0, int Bc)
{
    int i = blockIdx.x * 256 + threadIdx.x;
    if (i >= Bc * D) return;
    int b = i >> 7, d = i & 127;
    int idx = seqlen[b0 + b] - 1;
    out[(size_t)(b0 + b) * D + d] = bf2f(x[((size_t)b * SEQ + idx) * D + d]);
}

// ---------------------------------------------------------------------------
extern "C" void kernel_launch(void* const* d_in, const int* in_sizes, int n_in,
                              void* d_out, int out_size, void* d_ws, size_t ws_size,
                              hipStream_t stream)
{
    const float* token_emb  = (const float*)d_in[0];
    const float* emb_ln_g   = (const float*)d_in[1];
    const float* emb_ln_b   = (const float*)d_in[2];
    const float* params_log = (const float*)d_in[3];
    const float* in_wr      = (const float*)d_in[4];
    const float* in_wi      = (const float*)d_in[5];
    const float* in_br      = (const float*)d_in[6];
    const float* in_bi      = (const float*)d_in[7];
    const float* out_wr     = (const float*)d_in[8];
    const float* out_wi     = (const float*)d_in[9];
    const float* out_br     = (const float*)d_in[10];
    const float* lru_ln_g   = (const float*)d_in[12];
    const float* lru_ln_b   = (const float*)d_in[13];
    const float* w1         = (const float*)d_in[14];
    const float* b1         = (const float*)d_in[15];
    const float* w2         = (const float*)d_in[16];
    const float* b2         = (const float*)d_in[17];
    const float* ffn_ln_g   = (const float*)d_in[18];
    const float* ffn_ln_b   = (const float*)d_in[19];
    const int*   item_seq   = (const int*)d_in[20];
    const int*   item_seq_len = (const int*)d_in[21];
    float* out = (float*)d_out;

    char* ws = (char*)d_ws;
    ushort* Winb   = (ushort*)ws;                      ws += NLAY * 65536 * 2;
    ushort* W2effb = (ushort*)ws;                      ws += NLAY * 65536 * 2;
    ushort* w1b    = (ushort*)ws;                      ws += NLAY * 65536 * 2;
    ushort* w2b    = (ushort*)ws;                      ws += NLAY * 65536 * 2;
    float* lam_pow = (float*)ws;                       ws += NLAY * 65536 * 4;
    float* scale_in = (float*)ws;                      ws += NLAY * 512 * 4;
    float* bias_in  = (float*)ws;                      ws += NLAY * 512 * 4;
    size_t table_bytes = (size_t)(ws - (char*)d_ws);

    int Bc = B_TOT;
    while (Bc > 32) {
        size_t need = table_bytes + (size_t)Bc * SEQ * (D * 2 + 2 * DH * 2) + 1024;
        if (need <= ws_size) break;
        Bc >>= 1;
    }
    ushort* xb = (ushort*)ws;                          ws += (size_t)Bc * SEQ * D * 2;
    ushort* hb = (ushort*)ws;

    setup_params_kernel<<<NLAY, 256, 0, stream>>>(params_log, in_br, in_bi,
                                                  lam_pow, scale_in, bias_in);
    setup_weights_kernel<<<NLAY * 65536 / 256, 256, 0, stream>>>(
        in_wr, in_wi, out_wr, out_wi, w1, w2, Winb, W2effb, w1b, w2b);

    for (int b0 = 0; b0 < B_TOT; b0 += Bc) {
        int M = Bc * SEQ;
        embed_ln_kernel<<<M / 4, 256, 0, stream>>>(
            token_emb, item_seq + (size_t)b0 * SEQ, emb_ln_g, emb_ln_b, xb);

        for (int li = 0; li < NLAY; ++li) {
            // in-proj -> H layout
            gemm_bf16_kernel<0, false><<<dim3(M / 128, 4), 256, 0, stream>>>(
                xb, Winb + (size_t)li * 65536, hb, M, 2 * DH, D,
                scale_in + li * 512, bias_in + li * 512,
                (const ushort*)0, (const float*)0, (const float*)0);
            // exact tree scan (in place, H layout)
            lru_scan_kernel<<<dim3(8, Bc), 256, 0, stream>>>(
                hb, (const float2*)(lam_pow + (size_t)li * 65536),
                item_seq + (size_t)b0 * SEQ);
            // out-proj + bias + residual + LN -> bf16 x
            gemm_bf16_kernel<1, true><<<dim3(M / 128, 1), 256, 0, stream>>>(
                hb, W2effb + (size_t)li * 65536, xb, M, D, 2 * DH,
                out_br + li * D, (const float*)0, xb,
                lru_ln_g + li * D, lru_ln_b + li * D);
            // FFN1 + gelu
            gemm_bf16_kernel<2, false><<<dim3(M / 128, 4), 256, 0, stream>>>(
                xb, w1b + (size_t)li * DFF * D, hb, M, DFF, D,
                b1 + li * DFF, (const float*)0,
                (const ushort*)0, (const float*)0, (const float*)0);
            // FFN2 + bias + residual + LN -> bf16 x
            gemm_bf16_kernel<1, false><<<dim3(M / 128, 1), 256, 0, stream>>>(
                hb, w2b + (size_t)li * D * DFF, xb, M, D, DFF,
                b2 + li * D, (const float*)0, xb,
                ffn_ln_g + li * D, ffn_ln_b + li * D);
        }
        gather_kernel<<<(Bc * D + 255) / 256, 256, 0, stream>>>(
            xb, item_seq_len, out, b0, Bc);
    }
}

// Round 4
// 754.778 us; speedup vs baseline: 3.1425x; 1.2757x over previous
//
#include <hip/hip_runtime.h>
#include <hip/hip_bf16.h>
#include <math.h>

#define B_TOT 512
#define SEQ   200
#define D     128
#define DH    256
#define DFF   512
#define LPAD  256
#define PADL  56
#define NLAY  2
#define SCH   16   // channels per scan block

typedef __attribute__((ext_vector_type(8))) short bf16x8;
typedef __attribute__((ext_vector_type(4))) float floatx4;

static __device__ inline float bf2f(ushort u) {
    union { unsigned int i; float f; } v; v.i = ((unsigned int)u) << 16; return v.f;
}
static __device__ inline ushort f2bf(float x) {
    union { float f; unsigned int i; } v; v.f = x;
    unsigned int r = (v.i + 0x7FFFu + ((v.i >> 16) & 1u)) >> 16;   // RNE
    return (ushort)r;
}

// H layout: [b][g(8)][p(re/im)][s(200)][32 ch] bf16. k in 0..511: k<256 re, else im.
static __device__ inline size_t haddr(int b, int s, int k) {
    int p  = k >> 8;
    int ch = k & 255;
    int g  = ch >> 5;
    int cl = ch & 31;
    return (((((size_t)b * 8 + g) * 2 + p) * SEQ + s) * 32 + cl);
}

// ---------------------------------------------------------------------------
// lambda powers + in-proj epilogue scale/bias
// ---------------------------------------------------------------------------
__global__ void setup_params_kernel(const float* __restrict__ params_log,
                                    const float* __restrict__ in_br,
                                    const float* __restrict__ in_bi,
                                    float* __restrict__ lam_pow,   // [NLAY][128][256] float2
                                    float* __restrict__ scale_in,  // [NLAY][512]
                                    float* __restrict__ bias_in)   // [NLAY][512]
{
    int li = blockIdx.x;
    int c  = threadIdx.x;             // 256 threads
    const float* pl = params_log + (size_t)li * 3 * DH;
    float nu = expf(pl[c]);
    float th = expf(pl[DH + c]);
    float ga = expf(pl[2 * DH + c]);
    float mag = expf(-nu);
    float lr = mag * cosf(th);
    float lim = mag * sinf(th);
    float2* lp = (float2*)(lam_pow + (size_t)li * 65536);
    float pr = lr, pi = lim;
    lp[c] = make_float2(pr, pi);
    for (int k = 1; k < 128; ++k) {
        float nr = pr * lr - pi * lim;
        float ni = pr * lim + pi * lr;
        pr = nr; pi = ni;
        lp[(size_t)k * DH + c] = make_float2(pr, pi);
    }
    scale_in[li * 2 * DH + c]      = ga;
    scale_in[li * 2 * DH + DH + c] = ga;
    bias_in[li * 2 * DH + c]       = in_br[li * DH + c] * ga;
    bias_in[li * 2 * DH + DH + c]  = in_bi[li * DH + c] * ga;
}

__global__ void setup_weights_kernel(const float* __restrict__ in_wr,
                                     const float* __restrict__ in_wi,
                                     const float* __restrict__ out_wr,
                                     const float* __restrict__ out_wi,
                                     const float* __restrict__ w1,
                                     const float* __restrict__ w2,
                                     ushort* __restrict__ Winb,
                                     ushort* __restrict__ W2effb,
                                     ushort* __restrict__ w1b,
                                     ushort* __restrict__ w2b)
{
    int idx = blockIdx.x * blockDim.x + threadIdx.x;   // NLAY*65536
    int li = idx >> 16;
    int r  = idx & 65535;

    int n = r >> 7, d = r & 127;
    float wv = (n < DH) ? in_wr[((size_t)li * DH + n) * D + d]
                        : in_wi[((size_t)li * DH + (n - DH)) * D + d];
    Winb[idx] = f2bf(wv);

    int dd = r >> 9, cc = r & 511;
    float w2v = (cc < DH) ? out_wr[((size_t)li * D + dd) * DH + cc]
                          : -out_wi[((size_t)li * D + dd) * DH + (cc - DH)];
    W2effb[idx] = f2bf(w2v);

    w1b[idx] = f2bf(w1[idx]);
    w2b[idx] = f2bf(w2[idx]);
}

// ---------------------------------------------------------------------------
// Embedding gather + LayerNorm -> bf16 x
// ---------------------------------------------------------------------------
__global__ __launch_bounds__(256) void embed_ln_kernel(
    const float* __restrict__ emb, const int* __restrict__ seq,
    const float* __restrict__ g, const float* __restrict__ bt,
    ushort* __restrict__ x)
{
    int row  = blockIdx.x * 4 + (threadIdx.x >> 6);
    int lane = threadIdx.x & 63;
    int item = seq[row];
    float2 v = *(const float2*)(emb + (size_t)item * D + lane * 2);
    float s = v.x + v.y;
#pragma unroll
    for (int o = 32; o > 0; o >>= 1) s += __shfl_xor(s, o);
    float mu = s * (1.0f / D);
    float d0 = v.x - mu, d1 = v.y - mu;
    float vs = d0 * d0 + d1 * d1;
#pragma unroll
    for (int o = 32; o > 0; o >>= 1) vs += __shfl_xor(vs, o);
    float rstd = rsqrtf(vs * (1.0f / D) + 1e-5f);
    float2 gg = *(const float2*)(g + lane * 2);
    float2 bb = *(const float2*)(bt + lane * 2);
    ushort2 o2;
    o2.x = f2bf(d0 * rstd * gg.x + bb.x);
    o2.y = f2bf(d1 * rstd * gg.y + bb.y);
    *(ushort2*)(x + (size_t)row * D + lane * 2) = o2;
}

// ---------------------------------------------------------------------------
// Exact tree scan. Block = (gp, b): 16 complex channels of one batch element.
// 512 threads, 33 KB LDS -> 4 blocks/CU (32 waves/CU). fp32 LDS compute.
// ---------------------------------------------------------------------------
__global__ __launch_bounds__(512) void lru_scan_kernel(
    ushort* __restrict__ H,
    const float2* __restrict__ lam_pow,   // [128][256], entry k = lambda^{k+1}
    const int* __restrict__ seq)
{
    __shared__ float hR[LPAD][SCH];   // 16 KB
    __shared__ float hI[LPAD][SCH];   // 16 KB
    __shared__ int mk[LPAD];
    int gp = blockIdx.x;              // 0..15
    int g  = gp >> 1;
    int hc = (gp & 1) * SCH;
    int b  = blockIdx.y;
    int tid = threadIdx.x;

    if (tid < LPAD) {
        int t = tid;
        int m = 0;
        if (t >= PADL) m = (seq[(size_t)b * SEQ + (t - PADL)] > 0) ? 1 : 0;
        mk[t] = m;
    }
    for (int idx = tid; idx < PADL * SCH; idx += 512) {
        int t = idx >> 4, c = idx & 15;
        hR[t][c] = 0.f; hI[t][c] = 0.f;
    }
    ushort* base = H + (size_t)(b * 8 + g) * 2 * SEQ * 32 + hc;
    // load 2*200*16 ushorts as 1600 uint2 chunks
#pragma unroll
    for (int it = 0; it < 4; ++it) {
        int idx4 = it * 512 + tid;
        if (idx4 < 2 * SEQ * 4) {
            int q  = idx4 & 3;
            int ps = idx4 >> 2;
            int p  = ps >= SEQ;
            int s  = ps - p * SEQ;
            uint2 raw = *(const uint2*)(base + (size_t)ps * 32 + q * 4);
            int t = s + PADL;
            float* dst = (p ? &hI[0][0] : &hR[0][0]) + t * SCH + q * 4;
            dst[0] = bf2f((ushort)(raw.x & 0xffff));
            dst[1] = bf2f((ushort)(raw.x >> 16));
            dst[2] = bf2f((ushort)(raw.y & 0xffff));
            dst[3] = bf2f((ushort)(raw.y >> 16));
        }
    }
    __syncthreads();

    int c  = tid & 15;
    int tl = tid >> 4;                 // 32 groups
    const float2* lamg = lam_pow + gp * SCH + c;
    for (int i = 1; i <= 8; ++i) {
        int half = 1 << (i - 1);
#pragma unroll
        for (int k = 0; k < 4; ++k) {
            int u   = tl + 32 * k;
            int kb  = u >> (i - 1);
            int j   = u & (half - 1);
            int src = kb * (half << 1) + half - 1;
            if (mk[src]) {
                int t = src + 1 + j;
                float sr = hR[src][c], si = hI[src][c];
                float2 lp = lamg[(size_t)j * DH];
                hR[t][c] += lp.x * sr - lp.y * si;
                hI[t][c] += lp.x * si + lp.y * sr;
            }
        }
        __syncthreads();
    }

    // store back (real 200 positions only)
#pragma unroll
    for (int it = 0; it < 4; ++it) {
        int idx4 = it * 512 + tid;
        if (idx4 < 2 * SEQ * 4) {
            int q  = idx4 & 3;
            int ps = idx4 >> 2;
            int p  = ps >= SEQ;
            int s  = ps - p * SEQ;
            int t  = s + PADL;
            const float* srcp = (p ? &hI[0][0] : &hR[0][0]) + t * SCH + q * 4;
            uint2 raw;
            raw.x = (unsigned int)f2bf(srcp[0]) | ((unsigned int)f2bf(srcp[1]) << 16);
            raw.y = (unsigned int)f2bf(srcp[2]) | ((unsigned int)f2bf(srcp[3]) << 16);
            *(uint2*)(base + (size_t)ps * 32 + q * 4) = raw;
        }
    }
}

// ---------------------------------------------------------------------------
// bf16 MFMA GEMM, weights in A-slot / activations in B-slot.
// C(M,N) = act(M,K) @ W(N,K)^T + epilogue
// MODE 0: bf16 H-layout out = acc*e0[n] + e1[n]          (in-proj)
// MODE 1: bf16 out = LayerNorm(acc + e0[n] + res[m][n])  (out-proj / FFN2, N=128)
// MODE 2: bf16 out = gelu_exact(acc + e0[n])             (FFN1)
// AHL: activation operand read from H layout (out-proj).
// ---------------------------------------------------------------------------
template <int MODE, bool AHL>
__global__ __launch_bounds__(256) void gemm_bf16_kernel(
    const ushort* __restrict__ A, const ushort* __restrict__ W,
    ushort* __restrict__ Cout, int M, int N, int K,
    const float* __restrict__ e0, const float* __restrict__ e1,
    const ushort* __restrict__ res,
    const float* __restrict__ lng, const float* __restrict__ lnb)
{
    __shared__ char As[16384];   // 128 rows x 64 bf16, swizzled 16B chunks
    __shared__ char Bs[16384];
    __shared__ float2 lnS[2][128];
    int tid = threadIdx.x;
    int l = tid & 63, w = tid >> 6;
    int chh = w >> 1;        // channel half (0/1)
    int rh  = w & 1;         // act-row half (0/1)
    int lr = l & 15, lq = l >> 4;
    int m0 = blockIdx.x * 128, n0 = blockIdx.y * 128;

    int r_even = (2 * w) * 16 + lr;
    int r_odd  = (2 * w + 1) * 16 + lr;
    int sbE = 0, ssE = 0, sbO = 0, ssO = 0;
    if (AHL) {
        unsigned int ge = m0 + r_even, go = m0 + r_odd;
        sbE = ge / SEQ; ssE = ge - sbE * SEQ;
        sbO = go / SEQ; ssO = go - sbO * SEQ;
    }

    floatx4 acc[4][4];
#pragma unroll
    for (int i = 0; i < 4; ++i)
#pragma unroll
        for (int j = 0; j < 4; ++j) acc[i][j] = (floatx4)0.f;

    for (int k0 = 0; k0 < K; k0 += 64) {
#pragma unroll
        for (int it = 0; it < 4; ++it) {
            int r = (it < 2) ? r_even : r_odd;
            int c = (it & 1) * 4 + lq;
            uint4 va;
            if (AHL) {
                int sb = (it < 2) ? sbE : sbO;
                int ss = (it < 2) ? ssE : ssO;
                va = *(const uint4*)(A + haddr(sb, ss, k0 + c * 8));
            } else {
                va = *(const uint4*)(A + (size_t)(m0 + r) * K + k0 + c * 8);
            }
            *(uint4*)(As + r * 128 + ((c ^ (r & 7)) * 16)) = va;
            uint4 vb = *(const uint4*)(W + (size_t)(n0 + r) * K + k0 + c * 8);
            *(uint4*)(Bs + r * 128 + ((c ^ (r & 7)) * 16)) = vb;
        }
        __syncthreads();
#pragma unroll
        for (int kk = 0; kk < 2; ++kk) {
            bf16x8 wf[4], af[4];
            int ca = kk * 4 + lq;
#pragma unroll
            for (int i = 0; i < 4; ++i) {
                int rb = chh * 64 + i * 16 + lr;
                wf[i] = *(const bf16x8*)(Bs + rb * 128 + ((ca ^ (rb & 7)) * 16));
                int ra = rh * 64 + i * 16 + lr;
                af[i] = *(const bf16x8*)(As + ra * 128 + ((ca ^ (ra & 7)) * 16));
            }
#pragma unroll
            for (int i = 0; i < 4; ++i)
#pragma unroll
                for (int j = 0; j < 4; ++j)
                    acc[i][j] = __builtin_amdgcn_mfma_f32_16x16x32_bf16(
                        wf[i], af[j], acc[i][j], 0, 0, 0);
        }
        __syncthreads();
    }

    int chb[4], arow[4];
#pragma unroll
    for (int i = 0; i < 4; ++i) chb[i] = n0 + chh * 64 + i * 16 + lq * 4;
#pragma unroll
    for (int j = 0; j < 4; ++j) arow[j] = m0 + rh * 64 + j * 16 + lr;

    if (MODE == 1) {
        float4 bias[4], gv[4], bv[4];
#pragma unroll
        for (int i = 0; i < 4; ++i) {
            bias[i] = *(const float4*)(e0 + chb[i]);
            gv[i]   = *(const float4*)(lng + chb[i]);
            bv[i]   = *(const float4*)(lnb + chb[i]);
        }
#pragma unroll
        for (int j = 0; j < 4; ++j) {
#pragma unroll
            for (int i = 0; i < 4; ++i) {
                ushort4 r4 = *(const ushort4*)(res + (size_t)arow[j] * 128 + chb[i]);
                acc[i][j][0] += ((const float*)&bias[i])[0] + bf2f(r4.x);
                acc[i][j][1] += ((const float*)&bias[i])[1] + bf2f(r4.y);
                acc[i][j][2] += ((const float*)&bias[i])[2] + bf2f(r4.z);
                acc[i][j][3] += ((const float*)&bias[i])[3] + bf2f(r4.w);
            }
        }
#pragma unroll
        for (int j = 0; j < 4; ++j) {
            float s = 0.f, q = 0.f;
#pragma unroll
            for (int i = 0; i < 4; ++i)
#pragma unroll
                for (int reg = 0; reg < 4; ++reg) {
                    float v = acc[i][j][reg];
                    s += v; q += v * v;
                }
            s += __shfl_xor(s, 16); q += __shfl_xor(q, 16);
            s += __shfl_xor(s, 32); q += __shfl_xor(q, 32);
            if (lq == 0) lnS[chh][rh * 64 + j * 16 + lr] = make_float2(s, q);
        }
        __syncthreads();
#pragma unroll
        for (int j = 0; j < 4; ++j) {
            int rl = rh * 64 + j * 16 + lr;
            float2 s0 = lnS[0][rl], s1 = lnS[1][rl];
            float mu  = (s0.x + s1.x) * (1.0f / 128.0f);
            float var = (s0.y + s1.y) * (1.0f / 128.0f) - mu * mu;
            float rstd = rsqrtf(var + 1e-5f);
#pragma unroll
            for (int i = 0; i < 4; ++i) {
                ushort4 u4;
                u4.x = f2bf((acc[i][j][0] - mu) * rstd * ((const float*)&gv[i])[0] + ((const float*)&bv[i])[0]);
                u4.y = f2bf((acc[i][j][1] - mu) * rstd * ((const float*)&gv[i])[1] + ((const float*)&bv[i])[1]);
                u4.z = f2bf((acc[i][j][2] - mu) * rstd * ((const float*)&gv[i])[2] + ((const float*)&bv[i])[2]);
                u4.w = f2bf((acc[i][j][3] - mu) * rstd * ((const float*)&gv[i])[3] + ((const float*)&bv[i])[3]);
                *(ushort4*)(Cout + (size_t)arow[j] * 128 + chb[i]) = u4;
            }
        }
    } else if (MODE == 0) {
        float4 sc[4], bi[4];
#pragma unroll
        for (int i = 0; i < 4; ++i) {
            sc[i] = *(const float4*)(e0 + chb[i]);
            bi[i] = *(const float4*)(e1 + chb[i]);
        }
#pragma unroll
        for (int j = 0; j < 4; ++j) {
            unsigned int gr = arow[j];
            int b = gr / SEQ, s = gr - b * SEQ;
#pragma unroll
            for (int i = 0; i < 4; ++i) {
                ushort4 u4;
                u4.x = f2bf(acc[i][j][0] * ((const float*)&sc[i])[0] + ((const float*)&bi[i])[0]);
                u4.y = f2bf(acc[i][j][1] * ((const float*)&sc[i])[1] + ((const float*)&bi[i])[1]);
                u4.z = f2bf(acc[i][j][2] * ((const float*)&sc[i])[2] + ((const float*)&bi[i])[2]);
                u4.w = f2bf(acc[i][j][3] * ((const float*)&sc[i])[3] + ((const float*)&bi[i])[3]);
                *(ushort4*)(Cout + haddr(b, s, chb[i])) = u4;
            }
        }
    } else {
#pragma unroll
        for (int i = 0; i < 4; ++i) {
            float4 bi = *(const float4*)(e0 + chb[i]);
#pragma unroll
            for (int j = 0; j < 4; ++j) {
                ushort4 u4;
                float v;
                v = acc[i][j][0] + bi.x; u4.x = f2bf(0.5f * v * (1.0f + erff(v * 0.70710678118654752f)));
                v = acc[i][j][1] + bi.y; u4.y = f2bf(0.5f * v * (1.0f + erff(v * 0.70710678118654752f)));
                v = acc[i][j][2] + bi.z; u4.z = f2bf(0.5f * v * (1.0f + erff(v * 0.70710678118654752f)));
                v = acc[i][j][3] + bi.w; u4.w = f2bf(0.5f * v * (1.0f + erff(v * 0.70710678118654752f)));
                *(ushort4*)(Cout + (size_t)arow[j] * N + chb[i]) = u4;
            }
        }
    }
}

// ---------------------------------------------------------------------------
__global__ void gather_kernel(const ushort* __restrict__ x,
                              const int* __restrict__ seqlen,
                              float* __restrict__ out, int b0, int Bc)
{
    int i = blockIdx.x * 256 + threadIdx.x;
    if (i >= Bc * D) return;
    int b = i >> 7, d = i & 127;
    int idx = seqlen[b0 + b] - 1;
    out[(size_t)(b0 + b) * D + d] = bf2f(x[((size_t)b * SEQ + idx) * D + d]);
}

// ---------------------------------------------------------------------------
extern "C" void kernel_launch(void* const* d_in, const int* in_sizes, int n_in,
                              void* d_out, int out_size, void* d_ws, size_t ws_size,
                              hipStream_t stream)
{
    const float* token_emb  = (const float*)d_in[0];
    const float* emb_ln_g   = (const float*)d_in[1];
    const float* emb_ln_b   = (const float*)d_in[2];
    const float* params_log = (const float*)d_in[3];
    const float* in_wr      = (const float*)d_in[4];
    const float* in_wi      = (const float*)d_in[5];
    const float* in_br      = (const float*)d_in[6];
    const float* in_bi      = (const float*)d_in[7];
    const float* out_wr     = (const float*)d_in[8];
    const float* out_wi     = (const float*)d_in[9];
    const float* out_br     = (const float*)d_in[10];
    const float* lru_ln_g   = (const float*)d_in[12];
    const float* lru_ln_b   = (const float*)d_in[13];
    const float* w1         = (const float*)d_in[14];
    const float* b1         = (const float*)d_in[15];
    const float* w2         = (const float*)d_in[16];
    const float* b2         = (const float*)d_in[17];
    const float* ffn_ln_g   = (const float*)d_in[18];
    const float* ffn_ln_b   = (const float*)d_in[19];
    const int*   item_seq   = (const int*)d_in[20];
    const int*   item_seq_len = (const int*)d_in[21];
    float* out = (float*)d_out;

    char* ws = (char*)d_ws;
    ushort* Winb   = (ushort*)ws;                      ws += NLAY * 65536 * 2;
    ushort* W2effb = (ushort*)ws;                      ws += NLAY * 65536 * 2;
    ushort* w1b    = (ushort*)ws;                      ws += NLAY * 65536 * 2;
    ushort* w2b    = (ushort*)ws;                      ws += NLAY * 65536 * 2;
    float* lam_pow = (float*)ws;                       ws += NLAY * 65536 * 4;
    float* scale_in = (float*)ws;                      ws += NLAY * 512 * 4;
    float* bias_in  = (float*)ws;                      ws += NLAY * 512 * 4;
    size_t table_bytes = (size_t)(ws - (char*)d_ws);

    int Bc = B_TOT;
    while (Bc > 32) {
        size_t need = table_bytes + (size_t)Bc * SEQ * (D * 2 + 2 * DH * 2) + 1024;
        if (need <= ws_size) break;
        Bc >>= 1;
    }
    ushort* xb = (ushort*)ws;                          ws += (size_t)Bc * SEQ * D * 2;
    ushort* hb = (ushort*)ws;

    setup_params_kernel<<<NLAY, 256, 0, stream>>>(params_log, in_br, in_bi,
                                                  lam_pow, scale_in, bias_in);
    setup_weights_kernel<<<NLAY * 65536 / 256, 256, 0, stream>>>(
        in_wr, in_wi, out_wr, out_wi, w1, w2, Winb, W2effb, w1b, w2b);

    for (int b0 = 0; b0 < B_TOT; b0 += Bc) {
        int M = Bc * SEQ;
        embed_ln_kernel<<<M / 4, 256, 0, stream>>>(
            token_emb, item_seq + (size_t)b0 * SEQ, emb_ln_g, emb_ln_b, xb);

        for (int li = 0; li < NLAY; ++li) {
            // in-proj -> H layout
            gemm_bf16_kernel<0, false><<<dim3(M / 128, 4), 256, 0, stream>>>(
                xb, Winb + (size_t)li * 65536, hb, M, 2 * DH, D,
                scale_in + li * 512, bias_in + li * 512,
                (const ushort*)0, (const float*)0, (const float*)0);
            // exact tree scan (in place, H layout)
            lru_scan_kernel<<<dim3(16, Bc), 512, 0, stream>>>(
                hb, (const float2*)(lam_pow + (size_t)li * 65536),
                item_seq + (size_t)b0 * SEQ);
            // out-proj + bias + residual + LN -> bf16 x
            gemm_bf16_kernel<1, true><<<dim3(M / 128, 1), 256, 0, stream>>>(
                hb, W2effb + (size_t)li * 65536, xb, M, D, 2 * DH,
                out_br + li * D, (const float*)0, xb,
                lru_ln_g + li * D, lru_ln_b + li * D);
            // FFN1 + gelu
            gemm_bf16_kernel<2, false><<<dim3(M / 128, 4), 256, 0, stream>>>(
                xb, w1b + (size_t)li * DFF * D, hb, M, DFF, D,
                b1 + li * DFF, (const float*)0,
                (const ushort*)0, (const float*)0, (const float*)0);
            // FFN2 + bias + residual + LN -> bf16 x
            gemm_bf16_kernel<1, false><<<dim3(M / 128, 1), 256, 0, stream>>>(
                hb, w2b + (size_t)li * D * DFF, xb, M, D, DFF,
                b2 + li * D, (const float*)0, xb,
                ffn_ln_g + li * D, ffn_ln_b + li * D);
        }
        gather_kernel<<<(Bc * D + 255) / 256, 256, 0, stream>>>(
            xb, item_seq_len, out, b0, Bc);
    }
}

// Round 5
// 739.765 us; speedup vs baseline: 3.2063x; 1.0203x over previous
//
#include <hip/hip_runtime.h>
#include <hip/hip_bf16.h>
#include <math.h>

#define B_TOT 512
#define SEQ   200
#define D     128
#define DH    256
#define DFF   512
#define LPAD  256
#define PADL  56
#define NLAY  2

typedef __attribute__((ext_vector_type(8))) short bf16x8;
typedef __attribute__((ext_vector_type(4))) float floatx4;

static __device__ inline float bf2f(ushort u) {
    union { unsigned int i; float f; } v; v.i = ((unsigned int)u) << 16; return v.f;
}
static __device__ inline ushort f2bf(float x) {
    union { float f; unsigned int i; } v; v.f = x;
    unsigned int r = (v.i + 0x7FFFu + ((v.i >> 16) & 1u)) >> 16;   // RNE
    return (ushort)r;
}

// H layout: [b][g(8)][p(re/im)][s(200)][32 ch] bf16. k in 0..511: k<256 re, else im.
static __device__ inline size_t haddr(int b, int s, int k) {
    int p  = k >> 8;
    int ch = k & 255;
    int g  = ch >> 5;
    int cl = ch & 31;
    return (((((size_t)b * 8 + g) * 2 + p) * SEQ + s) * 32 + cl);
}

// ---------------------------------------------------------------------------
// lambda powers (TRANSPOSED: [ch][128] float2, entry j = lambda^{j+1})
// + in-proj epilogue scale/bias
// ---------------------------------------------------------------------------
__global__ void setup_params_kernel(const float* __restrict__ params_log,
                                    const float* __restrict__ in_br,
                                    const float* __restrict__ in_bi,
                                    float* __restrict__ lam_pow,   // [NLAY][256][128] float2
                                    float* __restrict__ scale_in,  // [NLAY][512]
                                    float* __restrict__ bias_in)   // [NLAY][512]
{
    int li = blockIdx.x;
    int c  = threadIdx.x;             // 256 threads
    const float* pl = params_log + (size_t)li * 3 * DH;
    float nu = expf(pl[c]);
    float th = expf(pl[DH + c]);
    float ga = expf(pl[2 * DH + c]);
    float mag = expf(-nu);
    float lr = mag * cosf(th);
    float lim = mag * sinf(th);
    float2* lp = (float2*)(lam_pow + (size_t)li * 65536) + (size_t)c * 128;
    float pr = lr, pi = lim;
    lp[0] = make_float2(pr, pi);
    for (int k = 1; k < 128; ++k) {
        float nr = pr * lr - pi * lim;
        float ni = pr * lim + pi * lr;
        pr = nr; pi = ni;
        lp[k] = make_float2(pr, pi);
    }
    scale_in[li * 2 * DH + c]      = ga;
    scale_in[li * 2 * DH + DH + c] = ga;
    bias_in[li * 2 * DH + c]       = in_br[li * DH + c] * ga;
    bias_in[li * 2 * DH + DH + c]  = in_bi[li * DH + c] * ga;
}

__global__ void setup_weights_kernel(const float* __restrict__ in_wr,
                                     const float* __restrict__ in_wi,
                                     const float* __restrict__ out_wr,
                                     const float* __restrict__ out_wi,
                                     const float* __restrict__ w1,
                                     const float* __restrict__ w2,
                                     ushort* __restrict__ Winb,
                                     ushort* __restrict__ W2effb,
                                     ushort* __restrict__ w1b,
                                     ushort* __restrict__ w2b)
{
    int idx = blockIdx.x * blockDim.x + threadIdx.x;   // NLAY*65536
    int li = idx >> 16;
    int r  = idx & 65535;

    int n = r >> 7, d = r & 127;
    float wv = (n < DH) ? in_wr[((size_t)li * DH + n) * D + d]
                        : in_wi[((size_t)li * DH + (n - DH)) * D + d];
    Winb[idx] = f2bf(wv);

    int dd = r >> 9, cc = r & 511;
    float w2v = (cc < DH) ? out_wr[((size_t)li * D + dd) * DH + cc]
                          : -out_wi[((size_t)li * D + dd) * DH + (cc - DH)];
    W2effb[idx] = f2bf(w2v);

    w1b[idx] = f2bf(w1[idx]);
    w2b[idx] = f2bf(w2[idx]);
}

// ---------------------------------------------------------------------------
// Embedding gather + LayerNorm -> bf16 x
// ---------------------------------------------------------------------------
__global__ __launch_bounds__(256) void embed_ln_kernel(
    const float* __restrict__ emb, const int* __restrict__ seq,
    const float* __restrict__ g, const float* __restrict__ bt,
    ushort* __restrict__ x)
{
    int row  = blockIdx.x * 4 + (threadIdx.x >> 6);
    int lane = threadIdx.x & 63;
    int item = seq[row];
    float2 v = *(const float2*)(emb + (size_t)item * D + lane * 2);
    float s = v.x + v.y;
#pragma unroll
    for (int o = 32; o > 0; o >>= 1) s += __shfl_xor(s, o);
    float mu = s * (1.0f / D);
    float d0 = v.x - mu, d1 = v.y - mu;
    float vs = d0 * d0 + d1 * d1;
#pragma unroll
    for (int o = 32; o > 0; o >>= 1) vs += __shfl_xor(vs, o);
    float rstd = rsqrtf(vs * (1.0f / D) + 1e-5f);
    float2 gg = *(const float2*)(g + lane * 2);
    float2 bb = *(const float2*)(bt + lane * 2);
    ushort2 o2;
    o2.x = f2bf(d0 * rstd * gg.x + bb.x);
    o2.y = f2bf(d1 * rstd * gg.y + bb.y);
    *(ushort2*)(x + (size_t)row * D + lane * 2) = o2;
}

// ---------------------------------------------------------------------------
// Exact tree scan, register-resident. Block = (gp, b): 16 complex channels.
// Thread owns 8 consecutive positions x 1 channel in registers.
// Levels 1-3 thread-internal; levels 4-8 via LDS end-value broadcast.
// Lambda powers staged to LDS (aliased into dead staging buffer).
// ---------------------------------------------------------------------------
__global__ __launch_bounds__(512) void lru_scan_kernel(
    ushort* __restrict__ H,
    const float2* __restrict__ lamT,      // [256][128], entry j = lambda^{j+1}
    const int* __restrict__ seq)
{
    __shared__ __align__(16) char smem[2 * LPAD * 17 * 4];   // 34816 B union
    __shared__ float mkf[LPAD];
    float* stR = (float*)smem;                    // [256][17]
    float* stI = stR + LPAD * 17;
    float2* lamS = (float2*)smem;                 // [16][130] = 16640 B (tree phase)
    float2* bc   = (float2*)(smem + 16 * 130 * 8);// [2][32][17] = 8704 B

    int gp = blockIdx.x;              // 0..15 ; block channels = gp*16 .. gp*16+15
    int g  = gp >> 1;
    int hc = (gp & 1) * 16;
    int b  = blockIdx.y;
    int tid = threadIdx.x;
    int c  = tid & 15;
    int tl = tid >> 4;                // 0..31
    int t0 = tl * 8;

    // lambda^1..4 for levels 1-3 (global, L2-resident; independent early load)
    const float2* myl = lamT + (size_t)(gp * 16 + c) * 128;
    float2 l14[4];
#pragma unroll
    for (int k = 0; k < 4; ++k) l14[k] = myl[k];

    if (tid < LPAD) {
        int t = tid;
        float m = 0.f;
        if (t >= PADL) m = (seq[(size_t)b * SEQ + (t - PADL)] > 0) ? 1.f : 0.f;
        mkf[t] = m;
    }
    // zero pad rows (t < 56, incl. pad col)
    for (int idx = tid; idx < PADL * 17; idx += 512) { stR[idx] = 0.f; stI[idx] = 0.f; }

    // coalesced load: 2*200*16 ushorts as uint2 per thread-iter
    ushort* baseg = H + (size_t)(b * 8 + g) * 2 * SEQ * 32 + hc;
#pragma unroll
    for (int it = 0; it < 4; ++it) {
        int idx4 = it * 512 + tid;
        if (idx4 < 2 * SEQ * 4) {
            int q  = idx4 & 3;
            int ps = idx4 >> 2;
            int p  = ps >= SEQ;
            int s  = ps - p * SEQ;
            uint2 raw = *(const uint2*)(baseg + (size_t)ps * 32 + q * 4);
            int t = s + PADL;
            float* dst = (p ? stI : stR) + t * 17 + q * 4;
            dst[0] = bf2f((ushort)(raw.x & 0xffff));
            dst[1] = bf2f((ushort)(raw.x >> 16));
            dst[2] = bf2f((ushort)(raw.y & 0xffff));
            dst[3] = bf2f((ushort)(raw.y >> 16));
        }
    }
    __syncthreads();

    // pull owned positions into registers
    float xr[8], xi[8], mf[8];
#pragma unroll
    for (int k = 0; k < 8; ++k) {
        xr[k] = stR[(t0 + k) * 17 + c];
        xi[k] = stI[(t0 + k) * 17 + c];
        mf[k] = mkf[t0 + k];
    }
    __syncthreads();   // stage region now dead -> reuse for lamS/bc

    // stage lambda slice [16 ch][128 powers] into LDS (16 KB, coalesced)
    {
        const float2* src = lamT + (size_t)gp * 16 * 128;
#pragma unroll
        for (int k = 0; k < 4; ++k) {
            int q = tid * 4 + k;       // 0..2047
            lamS[(q >> 7) * 130 + (q & 127)] = src[q];
        }
    }

    // levels 1-3: thread-internal
    {
        // level 1: src k=0,2,4,6 -> dst k+1, lambda^1
#pragma unroll
        for (int k = 0; k < 8; k += 2) {
            float sr = xr[k] * mf[k], si = xi[k] * mf[k];
            xr[k+1] += l14[0].x * sr - l14[0].y * si;
            xi[k+1] += l14[0].x * si + l14[0].y * sr;
        }
        // level 2: src k=1 -> dst 2,3 ; src k=5 -> dst 6,7 (lambda^1,2)
#pragma unroll
        for (int k = 1; k < 8; k += 4) {
            float sr = xr[k] * mf[k], si = xi[k] * mf[k];
            xr[k+1] += l14[0].x * sr - l14[0].y * si;
            xi[k+1] += l14[0].x * si + l14[0].y * sr;
            xr[k+2] += l14[1].x * sr - l14[1].y * si;
            xi[k+2] += l14[1].x * si + l14[1].y * sr;
        }
        // level 3: src k=3 -> dst 4..7 (lambda^1..4)
        {
            float sr = xr[3] * mf[3], si = xi[3] * mf[3];
#pragma unroll
            for (int j = 0; j < 4; ++j) {
                xr[4+j] += l14[j].x * sr - l14[j].y * si;
                xi[4+j] += l14[j].x * si + l14[j].y * sr;
            }
        }
    }

    // levels 4-8: LDS end-value broadcast, register FMAs
#pragma unroll
    for (int i = 4; i <= 8; ++i) {
        int half = 1 << (i - 1);
        int buf  = (i & 1) * 544;      // double buffer: [32][17] float2 each
        bc[buf + tl * 17 + c] = make_float2(xr[7], xi[7]);
        __syncthreads();               // also covers lamS staging at i==4
        int off = t0 & ((half << 1) - 1);
        if (off >= half) {
            int src = t0 - off + half - 1;
            float m = mkf[src];
            float2 sv = bc[buf + (src >> 3) * 17 + c];
            float sr = sv.x * m, si = sv.y * m;
            int e = off - half;        // lambda^{e+1..e+8} for positions t0..t0+7
            const float2* lp = lamS + c * 130 + e;
#pragma unroll
            for (int k = 0; k < 8; ++k) {
                float2 l = lp[k];
                xr[k] += l.x * sr - l.y * si;
                xi[k] += l.x * si + l.y * sr;
            }
        }
    }
    __syncthreads();   // all broadcast reads done -> stage region reusable

    // push registers back to stage
#pragma unroll
    for (int k = 0; k < 8; ++k) {
        stR[(t0 + k) * 17 + c] = xr[k];
        stI[(t0 + k) * 17 + c] = xi[k];
    }
    __syncthreads();

    // coalesced store (real 200 positions only)
#pragma unroll
    for (int it = 0; it < 4; ++it) {
        int idx4 = it * 512 + tid;
        if (idx4 < 2 * SEQ * 4) {
            int q  = idx4 & 3;
            int ps = idx4 >> 2;
            int p  = ps >= SEQ;
            int s  = ps - p * SEQ;
            int t  = s + PADL;
            const float* srcp = (p ? stI : stR) + t * 17 + q * 4;
            uint2 raw;
            raw.x = (unsigned int)f2bf(srcp[0]) | ((unsigned int)f2bf(srcp[1]) << 16);
            raw.y = (unsigned int)f2bf(srcp[2]) | ((unsigned int)f2bf(srcp[3]) << 16);
            *(uint2*)(baseg + (size_t)ps * 32 + q * 4) = raw;
        }
    }
}

// ---------------------------------------------------------------------------
// bf16 MFMA GEMM, weights in A-slot / activations in B-slot.
// C(M,N) = act(M,K) @ W(N,K)^T + epilogue
// MODE 0: bf16 H-layout out = acc*e0[n] + e1[n]          (in-proj)
// MODE 1: bf16 out = LayerNorm(acc + e0[n] + res[m][n])  (out-proj / FFN2, N=128)
// MODE 2: bf16 out = gelu_exact(acc + e0[n])             (FFN1)
// AHL: activation operand read from H layout (out-proj).
// ---------------------------------------------------------------------------
template <int MODE, bool AHL>
__global__ __launch_bounds__(256) void gemm_bf16_kernel(
    const ushort* __restrict__ A, const ushort* __restrict__ W,
    ushort* __restrict__ Cout, int M, int N, int K,
    const float* __restrict__ e0, const float* __restrict__ e1,
    const ushort* __restrict__ res,
    const float* __restrict__ lng, const float* __restrict__ lnb)
{
    __shared__ char As[16384];   // 128 rows x 64 bf16, swizzled 16B chunks
    __shared__ char Bs[16384];
    __shared__ float2 lnS[2][128];
    int tid = threadIdx.x;
    int l = tid & 63, w = tid >> 6;
    int chh = w >> 1;        // channel half (0/1)
    int rh  = w & 1;         // act-row half (0/1)
    int lr = l & 15, lq = l >> 4;
    int m0 = blockIdx.x * 128, n0 = blockIdx.y * 128;

    int r_even = (2 * w) * 16 + lr;
    int r_odd  = (2 * w + 1) * 16 + lr;
    int sbE = 0, ssE = 0, sbO = 0, ssO = 0;
    if (AHL) {
        unsigned int ge = m0 + r_even, go = m0 + r_odd;
        sbE = ge / SEQ; ssE = ge - sbE * SEQ;
        sbO = go / SEQ; ssO = go - sbO * SEQ;
    }

    floatx4 acc[4][4];
#pragma unroll
    for (int i = 0; i < 4; ++i)
#pragma unroll
        for (int j = 0; j < 4; ++j) acc[i][j] = (floatx4)0.f;

    for (int k0 = 0; k0 < K; k0 += 64) {
#pragma unroll
        for (int it = 0; it < 4; ++it) {
            int r = (it < 2) ? r_even : r_odd;
            int c = (it & 1) * 4 + lq;
            uint4 va;
            if (AHL) {
                int sb = (it < 2) ? sbE : sbO;
                int ss = (it < 2) ? ssE : ssO;
                va = *(const uint4*)(A + haddr(sb, ss, k0 + c * 8));
            } else {
                va = *(const uint4*)(A + (size_t)(m0 + r) * K + k0 + c * 8);
            }
            *(uint4*)(As + r * 128 + ((c ^ (r & 7)) * 16)) = va;
            uint4 vb = *(const uint4*)(W + (size_t)(n0 + r) * K + k0 + c * 8);
            *(uint4*)(Bs + r * 128 + ((c ^ (r & 7)) * 16)) = vb;
        }
        __syncthreads();
#pragma unroll
        for (int kk = 0; kk < 2; ++kk) {
            bf16x8 wf[4], af[4];
            int ca = kk * 4 + lq;
#pragma unroll
            for (int i = 0; i < 4; ++i) {
                int rb = chh * 64 + i * 16 + lr;
                wf[i] = *(const bf16x8*)(Bs + rb * 128 + ((ca ^ (rb & 7)) * 16));
                int ra = rh * 64 + i * 16 + lr;
                af[i] = *(const bf16x8*)(As + ra * 128 + ((ca ^ (ra & 7)) * 16));
            }
#pragma unroll
            for (int i = 0; i < 4; ++i)
#pragma unroll
                for (int j = 0; j < 4; ++j)
                    acc[i][j] = __builtin_amdgcn_mfma_f32_16x16x32_bf16(
                        wf[i], af[j], acc[i][j], 0, 0, 0);
        }
        __syncthreads();
    }

    int chb[4], arow[4];
#pragma unroll
    for (int i = 0; i < 4; ++i) chb[i] = n0 + chh * 64 + i * 16 + lq * 4;
#pragma unroll
    for (int j = 0; j < 4; ++j) arow[j] = m0 + rh * 64 + j * 16 + lr;

    if (MODE == 1) {
        float4 bias[4], gv[4], bv[4];
#pragma unroll
        for (int i = 0; i < 4; ++i) {
            bias[i] = *(const float4*)(e0 + chb[i]);
            gv[i]   = *(const float4*)(lng + chb[i]);
            bv[i]   = *(const float4*)(lnb + chb[i]);
        }
#pragma unroll
        for (int j = 0; j < 4; ++j) {
#pragma unroll
            for (int i = 0; i < 4; ++i) {
                ushort4 r4 = *(const ushort4*)(res + (size_t)arow[j] * 128 + chb[i]);
                acc[i][j][0] += ((const float*)&bias[i])[0] + bf2f(r4.x);
                acc[i][j][1] += ((const float*)&bias[i])[1] + bf2f(r4.y);
                acc[i][j][2] += ((const float*)&bias[i])[2] + bf2f(r4.z);
                acc[i][j][3] += ((const float*)&bias[i])[3] + bf2f(r4.w);
            }
        }
#pragma unroll
        for (int j = 0; j < 4; ++j) {
            float s = 0.f, q = 0.f;
#pragma unroll
            for (int i = 0; i < 4; ++i)
#pragma unroll
                for (int reg = 0; reg < 4; ++reg) {
                    float v = acc[i][j][reg];
                    s += v; q += v * v;
                }
            s += __shfl_xor(s, 16); q += __shfl_xor(q, 16);
            s += __shfl_xor(s, 32); q += __shfl_xor(q, 32);
            if (lq == 0) lnS[chh][rh * 64 + j * 16 + lr] = make_float2(s, q);
        }
        __syncthreads();
#pragma unroll
        for (int j = 0; j < 4; ++j) {
            int rl = rh * 64 + j * 16 + lr;
            float2 s0 = lnS[0][rl], s1 = lnS[1][rl];
            float mu  = (s0.x + s1.x) * (1.0f / 128.0f);
            float var = (s0.y + s1.y) * (1.0f / 128.0f) - mu * mu;
            float rstd = rsqrtf(var + 1e-5f);
#pragma unroll
            for (int i = 0; i < 4; ++i) {
                ushort4 u4;
                u4.x = f2bf((acc[i][j][0] - mu) * rstd * ((const float*)&gv[i])[0] + ((const float*)&bv[i])[0]);
                u4.y = f2bf((acc[i][j][1] - mu) * rstd * ((const float*)&gv[i])[1] + ((const float*)&bv[i])[1]);
                u4.z = f2bf((acc[i][j][2] - mu) * rstd * ((const float*)&gv[i])[2] + ((const float*)&bv[i])[2]);
                u4.w = f2bf((acc[i][j][3] - mu) * rstd * ((const float*)&gv[i])[3] + ((const float*)&bv[i])[3]);
                *(ushort4*)(Cout + (size_t)arow[j] * 128 + chb[i]) = u4;
            }
        }
    } else if (MODE == 0) {
        float4 sc[4], bi[4];
#pragma unroll
        for (int i = 0; i < 4; ++i) {
            sc[i] = *(const float4*)(e0 + chb[i]);
            bi[i] = *(const float4*)(e1 + chb[i]);
        }
#pragma unroll
        for (int j = 0; j < 4; ++j) {
            unsigned int gr = arow[j];
            int b = gr / SEQ, s = gr - b * SEQ;
#pragma unroll
            for (int i = 0; i < 4; ++i) {
                ushort4 u4;
                u4.x = f2bf(acc[i][j][0] * ((const float*)&sc[i])[0] + ((const float*)&bi[i])[0]);
                u4.y = f2bf(acc[i][j][1] * ((const float*)&sc[i])[1] + ((const float*)&bi[i])[1]);
                u4.z = f2bf(acc[i][j][2] * ((const float*)&sc[i])[2] + ((const float*)&bi[i])[2]);
                u4.w = f2bf(acc[i][j][3] * ((const float*)&sc[i])[3] + ((const float*)&bi[i])[3]);
                *(ushort4*)(Cout + haddr(b, s, chb[i])) = u4;
            }
        }
    } else {
#pragma unroll
        for (int i = 0; i < 4; ++i) {
            float4 bi = *(const float4*)(e0 + chb[i]);
#pragma unroll
            for (int j = 0; j < 4; ++j) {
                ushort4 u4;
                float v;
                v = acc[i][j][0] + bi.x; u4.x = f2bf(0.5f * v * (1.0f + erff(v * 0.70710678118654752f)));
                v = acc[i][j][1] + bi.y; u4.y = f2bf(0.5f * v * (1.0f + erff(v * 0.70710678118654752f)));
                v = acc[i][j][2] + bi.z; u4.z = f2bf(0.5f * v * (1.0f + erff(v * 0.70710678118654752f)));
                v = acc[i][j][3] + bi.w; u4.w = f2bf(0.5f * v * (1.0f + erff(v * 0.70710678118654752f)));
                *(ushort4*)(Cout + (size_t)arow[j] * N + chb[i]) = u4;
            }
        }
    }
}

// ---------------------------------------------------------------------------
__global__ void gather_kernel(const ushort* __restrict__ x,
                              const int* __restrict__ seqlen,
                              float* __restrict__ out, int b0, int Bc)
{
    int i = blockIdx.x * 256 + threadIdx.x;
    if (i >= Bc * D) return;
    int b = i >> 7, d = i & 127;
    int idx = seqlen[b0 + b] - 1;
    out[(size_t)(b0 + b) * D + d] = bf2f(x[((size_t)b * SEQ + idx) * D + d]);
}

// ---------------------------------------------------------------------------
extern "C" void kernel_launch(void* const* d_in, const int* in_sizes, int n_in,
                              void* d_out, int out_size, void* d_ws, size_t ws_size,
                              hipStream_t stream)
{
    const float* token_emb  = (const float*)d_in[0];
    const float* emb_ln_g   = (const float*)d_in[1];
    const float* emb_ln_b   = (const float*)d_in[2];
    const float* params_log = (const float*)d_in[3];
    const float* in_wr      = (const float*)d_in[4];
    const float* in_wi      = (const float*)d_in[5];
    const float* in_br      = (const float*)d_in[6];
    const float* in_bi      = (const float*)d_in[7];
    const float* out_wr     = (const float*)d_in[8];
    const float* out_wi     = (const float*)d_in[9];
    const float* out_br     = (const float*)d_in[10];
    const float* lru_ln_g   = (const float*)d_in[12];
    const float* lru_ln_b   = (const float*)d_in[13];
    const float* w1         = (const float*)d_in[14];
    const float* b1         = (const float*)d_in[15];
    const float* w2         = (const float*)d_in[16];
    const float* b2         = (const float*)d_in[17];
    const float* ffn_ln_g   = (const float*)d_in[18];
    const float* ffn_ln_b   = (const float*)d_in[19];
    const int*   item_seq   = (const int*)d_in[20];
    const int*   item_seq_len = (const int*)d_in[21];
    float* out = (float*)d_out;

    char* ws = (char*)d_ws;
    ushort* Winb   = (ushort*)ws;                      ws += NLAY * 65536 * 2;
    ushort* W2effb = (ushort*)ws;                      ws += NLAY * 65536 * 2;
    ushort* w1b    = (ushort*)ws;                      ws += NLAY * 65536 * 2;
    ushort* w2b    = (ushort*)ws;                      ws += NLAY * 65536 * 2;
    float* lam_pow = (float*)ws;                       ws += NLAY * 65536 * 4;
    float* scale_in = (float*)ws;                      ws += NLAY * 512 * 4;
    float* bias_in  = (float*)ws;                      ws += NLAY * 512 * 4;
    size_t table_bytes = (size_t)(ws - (char*)d_ws);

    int Bc = B_TOT;
    while (Bc > 32) {
        size_t need = table_bytes + (size_t)Bc * SEQ * (D * 2 + 2 * DH * 2) + 1024;
        if (need <= ws_size) break;
        Bc >>= 1;
    }
    ushort* xb = (ushort*)ws;                          ws += (size_t)Bc * SEQ * D * 2;
    ushort* hb = (ushort*)ws;

    setup_params_kernel<<<NLAY, 256, 0, stream>>>(params_log, in_br, in_bi,
                                                  lam_pow, scale_in, bias_in);
    setup_weights_kernel<<<NLAY * 65536 / 256, 256, 0, stream>>>(
        in_wr, in_wi, out_wr, out_wi, w1, w2, Winb, W2effb, w1b, w2b);

    for (int b0 = 0; b0 < B_TOT; b0 += Bc) {
        int M = Bc * SEQ;
        embed_ln_kernel<<<M / 4, 256, 0, stream>>>(
            token_emb, item_seq + (size_t)b0 * SEQ, emb_ln_g, emb_ln_b, xb);

        for (int li = 0; li < NLAY; ++li) {
            // in-proj -> H layout
            gemm_bf16_kernel<0, false><<<dim3(M / 128, 4), 256, 0, stream>>>(
                xb, Winb + (size_t)li * 65536, hb, M, 2 * DH, D,
                scale_in + li * 512, bias_in + li * 512,
                (const ushort*)0, (const float*)0, (const float*)0);
            // exact tree scan (in place, H layout, register-resident)
            lru_scan_kernel<<<dim3(16, Bc), 512, 0, stream>>>(
                hb, (const float2*)(lam_pow + (size_t)li * 65536),
                item_seq + (size_t)b0 * SEQ);
            // out-proj + bias + residual + LN -> bf16 x
            gemm_bf16_kernel<1, true><<<dim3(M / 128, 1), 256, 0, stream>>>(
                hb, W2effb + (size_t)li * 65536, xb, M, D, 2 * DH,
                out_br + li * D, (const float*)0, xb,
                lru_ln_g + li * D, lru_ln_b + li * D);
            // FFN1 + gelu
            gemm_bf16_kernel<2, false><<<dim3(M / 128, 4), 256, 0, stream>>>(
                xb, w1b + (size_t)li * DFF * D, hb, M, DFF, D,
                b1 + li * DFF, (const float*)0,
                (const ushort*)0, (const float*)0, (const float*)0);
            // FFN2 + bias + residual + LN -> bf16 x
            gemm_bf16_kernel<1, false><<<dim3(M / 128, 1), 256, 0, stream>>>(
                hb, w2b + (size_t)li * D * DFF, xb, M, D, DFF,
                b2 + li * D, (const float*)0, xb,
                ffn_ln_g + li * D, ffn_ln_b + li * D);
        }
        gather_kernel<<<(Bc * D + 255) / 256, 256, 0, stream>>>(
            xb, item_seq_len, out, b0, Bc);
    }
}

// Round 6
// 687.710 us; speedup vs baseline: 3.4490x; 1.0757x over previous
//
#include <hip/hip_runtime.h>
#include <hip/hip_bf16.h>
#include <math.h>

#define B_TOT 512
#define SEQ   200
#define D     128
#define DH    256
#define DFF   512
#define LPAD  256
#define PADL  56
#define NLAY  2
#define SST   18   // scan LDS row stride (floats)

typedef __attribute__((ext_vector_type(8))) short bf16x8;
typedef __attribute__((ext_vector_type(4))) float floatx4;

static __device__ inline float bf2f(ushort u) {
    union { unsigned int i; float f; } v; v.i = ((unsigned int)u) << 16; return v.f;
}
static __device__ inline float lo16(unsigned int u) {
    union { unsigned int i; float f; } v; v.i = u << 16; return v.f;
}
static __device__ inline float hi16(unsigned int u) {
    union { unsigned int i; float f; } v; v.i = u & 0xffff0000u; return v.f;
}
static __device__ inline ushort f2bf(float x) {
    union { float f; unsigned int i; } v; v.f = x;
    unsigned int r = (v.i + 0x7FFFu + ((v.i >> 16) & 1u)) >> 16;   // RNE
    return (ushort)r;
}
// HW packed f32x2 -> bf16x2 (v_cvt_pk_bf16_f32 on gfx950), RNE
static __device__ inline unsigned int pkbf(float a, float b) {
    union { __hip_bfloat162 h; unsigned int u; } v;
    v.h = __float22bfloat162_rn(make_float2(a, b));
    return v.u;
}

// H layout: [b][g(8)][p(re/im)][s(200)][32 ch] bf16. k in 0..511: k<256 re, else im.
static __device__ inline size_t haddr(int b, int s, int k) {
    int p  = k >> 8;
    int ch = k & 255;
    int g  = ch >> 5;
    int cl = ch & 31;
    return (((((size_t)b * 8 + g) * 2 + p) * SEQ + s) * 32 + cl);
}

// ---------------------------------------------------------------------------
// lambda powers (TRANSPOSED: [ch][128] float2, entry j = lambda^{j+1})
// + in-proj epilogue scale/bias
// ---------------------------------------------------------------------------
__global__ void setup_params_kernel(const float* __restrict__ params_log,
                                    const float* __restrict__ in_br,
                                    const float* __restrict__ in_bi,
                                    float* __restrict__ lam_pow,   // [NLAY][256][128] float2
                                    float* __restrict__ scale_in,  // [NLAY][512]
                                    float* __restrict__ bias_in)   // [NLAY][512]
{
    int li = blockIdx.x;
    int c  = threadIdx.x;             // 256 threads
    const float* pl = params_log + (size_t)li * 3 * DH;
    float nu = expf(pl[c]);
    float th = expf(pl[DH + c]);
    float ga = expf(pl[2 * DH + c]);
    float mag = expf(-nu);
    float lr = mag * cosf(th);
    float lim = mag * sinf(th);
    float2* lp = (float2*)(lam_pow + (size_t)li * 65536) + (size_t)c * 128;
    float pr = lr, pi = lim;
    lp[0] = make_float2(pr, pi);
    for (int k = 1; k < 128; ++k) {
        float nr = pr * lr - pi * lim;
        float ni = pr * lim + pi * lr;
        pr = nr; pi = ni;
        lp[k] = make_float2(pr, pi);
    }
    scale_in[li * 2 * DH + c]      = ga;
    scale_in[li * 2 * DH + DH + c] = ga;
    bias_in[li * 2 * DH + c]       = in_br[li * DH + c] * ga;
    bias_in[li * 2 * DH + DH + c]  = in_bi[li * DH + c] * ga;
}

__global__ void setup_weights_kernel(const float* __restrict__ in_wr,
                                     const float* __restrict__ in_wi,
                                     const float* __restrict__ out_wr,
                                     const float* __restrict__ out_wi,
                                     const float* __restrict__ w1,
                                     const float* __restrict__ w2,
                                     ushort* __restrict__ Winb,
                                     ushort* __restrict__ W2effb,
                                     ushort* __restrict__ w1b,
                                     ushort* __restrict__ w2b)
{
    int idx = blockIdx.x * blockDim.x + threadIdx.x;   // NLAY*65536
    int li = idx >> 16;
    int r  = idx & 65535;

    int n = r >> 7, d = r & 127;
    float wv = (n < DH) ? in_wr[((size_t)li * DH + n) * D + d]
                        : in_wi[((size_t)li * DH + (n - DH)) * D + d];
    Winb[idx] = f2bf(wv);

    int dd = r >> 9, cc = r & 511;
    float w2v = (cc < DH) ? out_wr[((size_t)li * D + dd) * DH + cc]
                          : -out_wi[((size_t)li * D + dd) * DH + (cc - DH)];
    W2effb[idx] = f2bf(w2v);

    w1b[idx] = f2bf(w1[idx]);
    w2b[idx] = f2bf(w2[idx]);
}

// ---------------------------------------------------------------------------
// Embedding gather + LayerNorm -> bf16 x
// ---------------------------------------------------------------------------
__global__ __launch_bounds__(256) void embed_ln_kernel(
    const float* __restrict__ emb, const int* __restrict__ seq,
    const float* __restrict__ g, const float* __restrict__ bt,
    ushort* __restrict__ x)
{
    int row  = blockIdx.x * 4 + (threadIdx.x >> 6);
    int lane = threadIdx.x & 63;
    int item = seq[row];
    float2 v = *(const float2*)(emb + (size_t)item * D + lane * 2);
    float s = v.x + v.y;
#pragma unroll
    for (int o = 32; o > 0; o >>= 1) s += __shfl_xor(s, o);
    float mu = s * (1.0f / D);
    float d0 = v.x - mu, d1 = v.y - mu;
    float vs = d0 * d0 + d1 * d1;
#pragma unroll
    for (int o = 32; o > 0; o >>= 1) vs += __shfl_xor(vs, o);
    float rstd = rsqrtf(vs * (1.0f / D) + 1e-5f);
    float2 gg = *(const float2*)(g + lane * 2);
    float2 bb = *(const float2*)(bt + lane * 2);
    unsigned int o2 = pkbf(d0 * rstd * gg.x + bb.x, d1 * rstd * gg.y + bb.y);
    *(unsigned int*)(x + (size_t)row * D + lane * 2) = o2;
}

// ---------------------------------------------------------------------------
// Exact tree scan, register-resident. Block = (gp, b): 16 complex channels.
// Thread owns 8 consecutive positions x 1 channel in registers.
// Levels 1-3 thread-internal; levels 4-8 via LDS end-value broadcast.
// Stride-18 staging: float2 LDS ops, 2-way (free) bank pattern.
// ---------------------------------------------------------------------------
__global__ __launch_bounds__(512) void lru_scan_kernel(
    ushort* __restrict__ H,
    const float2* __restrict__ lamT,      // [256][128], entry j = lambda^{j+1}
    const int* __restrict__ seq)
{
    __shared__ __align__(16) char smem[2 * LPAD * SST * 4];   // 36864 B union
    __shared__ float mkf[LPAD];
    float* stR = (float*)smem;                    // [256][SST]
    float* stI = stR + LPAD * SST;
    float2* lamS = (float2*)smem;                 // [16][130] = 16640 B (tree phase)
    float2* bc   = (float2*)(smem + 16 * 130 * 8);// [2][32][17] float2 = 8688 B

    int gp = blockIdx.x;              // 0..15 ; block channels = gp*16 .. gp*16+15
    int g  = gp >> 1;
    int hc = (gp & 1) * 16;
    int b  = blockIdx.y;
    int tid = threadIdx.x;
    int c  = tid & 15;
    int tl = tid >> 4;                // 0..31
    int t0 = tl * 8;

    const float2* myl = lamT + (size_t)(gp * 16 + c) * 128;
    float2 l14[4];
#pragma unroll
    for (int k = 0; k < 4; ++k) l14[k] = myl[k];

    if (tid < LPAD) {
        int t = tid;
        float m = 0.f;
        if (t >= PADL) m = (seq[(size_t)b * SEQ + (t - PADL)] > 0) ? 1.f : 0.f;
        mkf[t] = m;
    }
    for (int idx = tid; idx < PADL * SST; idx += 512) { stR[idx] = 0.f; stI[idx] = 0.f; }

    // coalesced load: 2*200*16 ushorts as uint2 per thread-iter, float2 LDS writes
    ushort* baseg = H + (size_t)(b * 8 + g) * 2 * SEQ * 32 + hc;
#pragma unroll
    for (int it = 0; it < 4; ++it) {
        int idx4 = it * 512 + tid;
        if (idx4 < 2 * SEQ * 4) {
            int q  = idx4 & 3;
            int ps = idx4 >> 2;
            int p  = ps >= SEQ;
            int s  = ps - p * SEQ;
            uint2 raw = *(const uint2*)(baseg + (size_t)ps * 32 + q * 4);
            int t = s + PADL;
            float* dst = (p ? stI : stR) + t * SST + q * 4;
            *(float2*)(dst)     = make_float2(lo16(raw.x), hi16(raw.x));
            *(float2*)(dst + 2) = make_float2(lo16(raw.y), hi16(raw.y));
        }
    }
    __syncthreads();

    // pull owned positions into registers
    float xr[8], xi[8], mf[8];
#pragma unroll
    for (int k = 0; k < 8; ++k) {
        xr[k] = stR[(t0 + k) * SST + c];
        xi[k] = stI[(t0 + k) * SST + c];
        mf[k] = mkf[t0 + k];
    }
    __syncthreads();   // stage region now dead -> reuse for lamS/bc

    // stage lambda slice [16 ch][128 powers] into LDS (coalesced)
    {
        const float2* src = lamT + (size_t)gp * 16 * 128;
#pragma unroll
        for (int k = 0; k < 4; ++k) {
            int q = tid * 4 + k;       // 0..2047
            lamS[(q >> 7) * 130 + (q & 127)] = src[q];
        }
    }

    // levels 1-3: thread-internal
    {
#pragma unroll
        for (int k = 0; k < 8; k += 2) {
            float sr = xr[k] * mf[k], si = xi[k] * mf[k];
            xr[k+1] += l14[0].x * sr - l14[0].y * si;
            xi[k+1] += l14[0].x * si + l14[0].y * sr;
        }
#pragma unroll
        for (int k = 1; k < 8; k += 4) {
            float sr = xr[k] * mf[k], si = xi[k] * mf[k];
            xr[k+1] += l14[0].x * sr - l14[0].y * si;
            xi[k+1] += l14[0].x * si + l14[0].y * sr;
            xr[k+2] += l14[1].x * sr - l14[1].y * si;
            xi[k+2] += l14[1].x * si + l14[1].y * sr;
        }
        {
            float sr = xr[3] * mf[3], si = xi[3] * mf[3];
#pragma unroll
            for (int j = 0; j < 4; ++j) {
                xr[4+j] += l14[j].x * sr - l14[j].y * si;
                xi[4+j] += l14[j].x * si + l14[j].y * sr;
            }
        }
    }

    // levels 4-8: LDS end-value broadcast, register FMAs
#pragma unroll
    for (int i = 4; i <= 8; ++i) {
        int half = 1 << (i - 1);
        int buf  = (i & 1) * 544;      // double buffer: [32][17] float2 each
        bc[buf + tl * 17 + c] = make_float2(xr[7], xi[7]);
        __syncthreads();               // also covers lamS staging at i==4
        int off = t0 & ((half << 1) - 1);
        if (off >= half) {
            int src = t0 - off + half - 1;
            float m = mkf[src];
            float2 sv = bc[buf + (src >> 3) * 17 + c];
            float sr = sv.x * m, si = sv.y * m;
            int e = off - half;
            const float2* lp = lamS + c * 130 + e;
#pragma unroll
            for (int k = 0; k < 8; ++k) {
                float2 l = lp[k];
                xr[k] += l.x * sr - l.y * si;
                xi[k] += l.x * si + l.y * sr;
            }
        }
    }
    __syncthreads();   // all broadcast reads done -> stage region reusable

    // push registers back to stage
#pragma unroll
    for (int k = 0; k < 8; ++k) {
        stR[(t0 + k) * SST + c] = xr[k];
        stI[(t0 + k) * SST + c] = xi[k];
    }
    __syncthreads();

    // coalesced store (real 200 positions only)
#pragma unroll
    for (int it = 0; it < 4; ++it) {
        int idx4 = it * 512 + tid;
        if (idx4 < 2 * SEQ * 4) {
            int q  = idx4 & 3;
            int ps = idx4 >> 2;
            int p  = ps >= SEQ;
            int s  = ps - p * SEQ;
            int t  = s + PADL;
            const float* sp = (p ? stI : stR) + t * SST + q * 4;
            float2 a = *(const float2*)(sp);
            float2 d = *(const float2*)(sp + 2);
            uint2 raw;
            raw.x = pkbf(a.x, a.y);
            raw.y = pkbf(d.x, d.y);
            *(uint2*)(baseg + (size_t)ps * 32 + q * 4) = raw;
        }
    }
}

// ---------------------------------------------------------------------------
// bf16 MFMA GEMM, weights in A-slot / activations in B-slot.
// MODE 0: bf16 H-layout out = acc*e0[n] + e1[n]          (in-proj)
// MODE 1: bf16 out = LayerNorm(acc + e0[n] + res[m][n])  (out-proj, N=128)
// AHL: activation operand read from H layout (out-proj).
// ---------------------------------------------------------------------------
template <int MODE, bool AHL>
__global__ __launch_bounds__(256) void gemm_bf16_kernel(
    const ushort* __restrict__ A, const ushort* __restrict__ W,
    ushort* __restrict__ Cout, int M, int N, int K,
    const float* __restrict__ e0, const float* __restrict__ e1,
    const ushort* __restrict__ res,
    const float* __restrict__ lng, const float* __restrict__ lnb)
{
    __shared__ char As[16384];   // 128 rows x 64 bf16, swizzled 16B chunks
    __shared__ char Bs[16384];
    __shared__ float2 lnS[2][128];
    int tid = threadIdx.x;
    int l = tid & 63, w = tid >> 6;
    int chh = w >> 1;        // channel half (0/1)
    int rh  = w & 1;         // act-row half (0/1)
    int lr = l & 15, lq = l >> 4;
    int m0 = blockIdx.x * 128, n0 = blockIdx.y * 128;

    int r_even = (2 * w) * 16 + lr;
    int r_odd  = (2 * w + 1) * 16 + lr;
    int sbE = 0, ssE = 0, sbO = 0, ssO = 0;
    if (AHL) {
        unsigned int ge = m0 + r_even, go = m0 + r_odd;
        sbE = ge / SEQ; ssE = ge - sbE * SEQ;
        sbO = go / SEQ; ssO = go - sbO * SEQ;
    }

    floatx4 acc[4][4];
#pragma unroll
    for (int i = 0; i < 4; ++i)
#pragma unroll
        for (int j = 0; j < 4; ++j) acc[i][j] = (floatx4)0.f;

    for (int k0 = 0; k0 < K; k0 += 64) {
#pragma unroll
        for (int it = 0; it < 4; ++it) {
            int r = (it < 2) ? r_even : r_odd;
            int c = (it & 1) * 4 + lq;
            uint4 va;
            if (AHL) {
                int sb = (it < 2) ? sbE : sbO;
                int ss = (it < 2) ? ssE : ssO;
                va = *(const uint4*)(A + haddr(sb, ss, k0 + c * 8));
            } else {
                va = *(const uint4*)(A + (size_t)(m0 + r) * K + k0 + c * 8);
            }
            *(uint4*)(As + r * 128 + ((c ^ (r & 7)) * 16)) = va;
            uint4 vb = *(const uint4*)(W + (size_t)(n0 + r) * K + k0 + c * 8);
            *(uint4*)(Bs + r * 128 + ((c ^ (r & 7)) * 16)) = vb;
        }
        __syncthreads();
#pragma unroll
        for (int kk = 0; kk < 2; ++kk) {
            bf16x8 wf[4], af[4];
            int ca = kk * 4 + lq;
#pragma unroll
            for (int i = 0; i < 4; ++i) {
                int rb = chh * 64 + i * 16 + lr;
                wf[i] = *(const bf16x8*)(Bs + rb * 128 + ((ca ^ (rb & 7)) * 16));
                int ra = rh * 64 + i * 16 + lr;
                af[i] = *(const bf16x8*)(As + ra * 128 + ((ca ^ (ra & 7)) * 16));
            }
#pragma unroll
            for (int i = 0; i < 4; ++i)
#pragma unroll
                for (int j = 0; j < 4; ++j)
                    acc[i][j] = __builtin_amdgcn_mfma_f32_16x16x32_bf16(
                        wf[i], af[j], acc[i][j], 0, 0, 0);
        }
        __syncthreads();
    }

    int chb[4], arow[4];
#pragma unroll
    for (int i = 0; i < 4; ++i) chb[i] = n0 + chh * 64 + i * 16 + lq * 4;
#pragma unroll
    for (int j = 0; j < 4; ++j) arow[j] = m0 + rh * 64 + j * 16 + lr;

    if (MODE == 1) {
        float4 bias[4], gv[4], bv[4];
#pragma unroll
        for (int i = 0; i < 4; ++i) {
            bias[i] = *(const float4*)(e0 + chb[i]);
            gv[i]   = *(const float4*)(lng + chb[i]);
            bv[i]   = *(const float4*)(lnb + chb[i]);
        }
#pragma unroll
        for (int j = 0; j < 4; ++j) {
#pragma unroll
            for (int i = 0; i < 4; ++i) {
                ushort4 r4 = *(const ushort4*)(res + (size_t)arow[j] * 128 + chb[i]);
                acc[i][j][0] += ((const float*)&bias[i])[0] + bf2f(r4.x);
                acc[i][j][1] += ((const float*)&bias[i])[1] + bf2f(r4.y);
                acc[i][j][2] += ((const float*)&bias[i])[2] + bf2f(r4.z);
                acc[i][j][3] += ((const float*)&bias[i])[3] + bf2f(r4.w);
            }
        }
#pragma unroll
        for (int j = 0; j < 4; ++j) {
            float s = 0.f, q = 0.f;
#pragma unroll
            for (int i = 0; i < 4; ++i)
#pragma unroll
                for (int reg = 0; reg < 4; ++reg) {
                    float v = acc[i][j][reg];
                    s += v; q += v * v;
                }
            s += __shfl_xor(s, 16); q += __shfl_xor(q, 16);
            s += __shfl_xor(s, 32); q += __shfl_xor(q, 32);
            if (lq == 0) lnS[chh][rh * 64 + j * 16 + lr] = make_float2(s, q);
        }
        __syncthreads();
#pragma unroll
        for (int j = 0; j < 4; ++j) {
            int rl = rh * 64 + j * 16 + lr;
            float2 s0 = lnS[0][rl], s1 = lnS[1][rl];
            float mu  = (s0.x + s1.x) * (1.0f / 128.0f);
            float var = (s0.y + s1.y) * (1.0f / 128.0f) - mu * mu;
            float rstd = rsqrtf(var + 1e-5f);
#pragma unroll
            for (int i = 0; i < 4; ++i) {
                uint2 u;
                u.x = pkbf((acc[i][j][0] - mu) * rstd * ((const float*)&gv[i])[0] + ((const float*)&bv[i])[0],
                           (acc[i][j][1] - mu) * rstd * ((const float*)&gv[i])[1] + ((const float*)&bv[i])[1]);
                u.y = pkbf((acc[i][j][2] - mu) * rstd * ((const float*)&gv[i])[2] + ((const float*)&bv[i])[2],
                           (acc[i][j][3] - mu) * rstd * ((const float*)&gv[i])[3] + ((const float*)&bv[i])[3]);
                *(uint2*)(Cout + (size_t)arow[j] * 128 + chb[i]) = u;
            }
        }
    } else {   // MODE 0
        float4 sc[4], bi[4];
#pragma unroll
        for (int i = 0; i < 4; ++i) {
            sc[i] = *(const float4*)(e0 + chb[i]);
            bi[i] = *(const float4*)(e1 + chb[i]);
        }
#pragma unroll
        for (int j = 0; j < 4; ++j) {
            unsigned int gr = arow[j];
            int b = gr / SEQ, s = gr - b * SEQ;
#pragma unroll
            for (int i = 0; i < 4; ++i) {
                uint2 u;
                u.x = pkbf(acc[i][j][0] * ((const float*)&sc[i])[0] + ((const float*)&bi[i])[0],
                           acc[i][j][1] * ((const float*)&sc[i])[1] + ((const float*)&bi[i])[1]);
                u.y = pkbf(acc[i][j][2] * ((const float*)&sc[i])[2] + ((const float*)&bi[i])[2],
                           acc[i][j][3] * ((const float*)&sc[i])[3] + ((const float*)&bi[i])[3]);
                *(uint2*)(Cout + haddr(b, s, chb[i])) = u;
            }
        }
    }
}

// ---------------------------------------------------------------------------
// Fused FFN: out = LN(x + b2 + W2 @ gelu(W1 @ x + b1)).
// 64-row tile, P tile (64x128 per ffc chunk) round-trips through LDS.
// K-summation order identical to the unfused version (32-granule, monotone).
// ---------------------------------------------------------------------------
__global__ __launch_bounds__(256) void ffn_fused_kernel(
    const ushort* __restrict__ X, const ushort* __restrict__ W1,
    const ushort* __restrict__ W2, ushort* __restrict__ Out,
    const float* __restrict__ b1, const float* __restrict__ b2,
    const float* __restrict__ lng, const float* __restrict__ lnb)
{
    __shared__ char As[16384];          // [2 khalf][64 rows][64K] swizzled
    __shared__ char Bs[16384];          // [128 rows][64K] swizzled
    __shared__ ushort Ps[64 * 136];     // P tile, row stride 136 (16B-aligned rows)
    __shared__ float2 lnS[2][64];
    int tid = threadIdx.x;
    int l = tid & 63, w = tid >> 6;
    int chh = w >> 1, rh = w & 1;
    int lr = l & 15, lq = l >> 4;
    int m0 = blockIdx.x * 64;

    // stage x tile (64 rows x 128 K) once
#pragma unroll
    for (int it = 0; it < 4; ++it) {
        int idx = it * 256 + tid;
        int half = idx >> 9, rem = idx & 511;
        int r = rem >> 3, c = rem & 7;
        uint4 v = *(const uint4*)(X + (size_t)(m0 + r) * 128 + half * 64 + c * 8);
        *(uint4*)(As + half * 8192 + r * 128 + ((c ^ (r & 7)) * 16)) = v;
    }

    floatx4 acc2[4][2];
#pragma unroll
    for (int i = 0; i < 4; ++i)
#pragma unroll
        for (int j = 0; j < 2; ++j) acc2[i][j] = (floatx4)0.f;
    __syncthreads();

    for (int ffc = 0; ffc < 4; ++ffc) {
        floatx4 acc1[4][2];
#pragma unroll
        for (int i = 0; i < 4; ++i)
#pragma unroll
            for (int j = 0; j < 2; ++j) acc1[i][j] = (floatx4)0.f;

        // ---- FFN1: P = x @ W1chunk^T
        for (int kh = 0; kh < 2; ++kh) {
            if (ffc | kh) __syncthreads();   // protect Bs/Ps from prior reads
#pragma unroll
            for (int it = 0; it < 4; ++it) {
                int idx = it * 256 + tid;
                int r = idx >> 3, c = idx & 7;
                uint4 v = *(const uint4*)(W1 + (size_t)(ffc * 128 + r) * 128 + kh * 64 + c * 8);
                *(uint4*)(Bs + r * 128 + ((c ^ (r & 7)) * 16)) = v;
            }
            __syncthreads();
#pragma unroll
            for (int kk = 0; kk < 2; ++kk) {
                int ca = kk * 4 + lq;
                bf16x8 wf[4], af[2];
#pragma unroll
                for (int i = 0; i < 4; ++i) {
                    int rb = chh * 64 + i * 16 + lr;
                    wf[i] = *(const bf16x8*)(Bs + rb * 128 + ((ca ^ (rb & 7)) * 16));
                }
#pragma unroll
                for (int j = 0; j < 2; ++j) {
                    int ra = rh * 32 + j * 16 + lr;
                    af[j] = *(const bf16x8*)(As + kh * 8192 + ra * 128 + ((ca ^ (ra & 7)) * 16));
                }
#pragma unroll
                for (int i = 0; i < 4; ++i)
#pragma unroll
                    for (int j = 0; j < 2; ++j)
                        acc1[i][j] = __builtin_amdgcn_mfma_f32_16x16x32_bf16(
                            wf[i], af[j], acc1[i][j], 0, 0, 0);
            }
        }
        __syncthreads();   // last W1 reads done; Ps(prev ffc) reads long done

        // ---- gelu -> Ps (bf16, B-operand-ready layout)
#pragma unroll
        for (int j = 0; j < 2; ++j) {
            int rowl = rh * 32 + j * 16 + lr;
#pragma unroll
            for (int i = 0; i < 4; ++i) {
                int ch0 = chh * 64 + i * 16 + lq * 4;
                float4 bv = *(const float4*)(b1 + ffc * 128 + ch0);
                float g0, g1, g2, g3, v;
                v = acc1[i][j][0] + bv.x; g0 = 0.5f * v * (1.0f + erff(v * 0.70710678118654752f));
                v = acc1[i][j][1] + bv.y; g1 = 0.5f * v * (1.0f + erff(v * 0.70710678118654752f));
                v = acc1[i][j][2] + bv.z; g2 = 0.5f * v * (1.0f + erff(v * 0.70710678118654752f));
                v = acc1[i][j][3] + bv.w; g3 = 0.5f * v * (1.0f + erff(v * 0.70710678118654752f));
                uint2 u; u.x = pkbf(g0, g1); u.y = pkbf(g2, g3);
                *(uint2*)(Ps + rowl * 136 + ch0) = u;
            }
        }

        // ---- FFN2: acc2 += W2chunk @ P
        for (int kh = 0; kh < 2; ++kh) {
            if (kh) __syncthreads();
#pragma unroll
            for (int it = 0; it < 4; ++it) {
                int idx = it * 256 + tid;
                int r = idx >> 3, c = idx & 7;
                uint4 v = *(const uint4*)(W2 + (size_t)r * 512 + ffc * 128 + kh * 64 + c * 8);
                *(uint4*)(Bs + r * 128 + ((c ^ (r & 7)) * 16)) = v;
            }
            __syncthreads();   // Bs (+Ps at kh==0) visible
#pragma unroll
            for (int kk = 0; kk < 2; ++kk) {
                int ca = kk * 4 + lq;
                bf16x8 wf[4], af[2];
#pragma unroll
                for (int i = 0; i < 4; ++i) {
                    int rb = chh * 64 + i * 16 + lr;
                    wf[i] = *(const bf16x8*)(Bs + rb * 128 + ((ca ^ (rb & 7)) * 16));
                }
#pragma unroll
                for (int j = 0; j < 2; ++j) {
                    int rowl = rh * 32 + j * 16 + lr;
                    af[j] = *(const bf16x8*)(Ps + rowl * 136 + kh * 64 + kk * 32 + lq * 8);
                }
#pragma unroll
                for (int i = 0; i < 4; ++i)
#pragma unroll
                    for (int j = 0; j < 2; ++j)
                        acc2[i][j] = __builtin_amdgcn_mfma_f32_16x16x32_bf16(
                            wf[i], af[j], acc2[i][j], 0, 0, 0);
            }
        }
    }

    // ---- epilogue: + b2 + residual, LayerNorm, store
    int chb[4], arow[2];
#pragma unroll
    for (int i = 0; i < 4; ++i) chb[i] = chh * 64 + i * 16 + lq * 4;
#pragma unroll
    for (int j = 0; j < 2; ++j) arow[j] = m0 + rh * 32 + j * 16 + lr;

    float4 bias[4], gv[4], bv[4];
#pragma unroll
    for (int i = 0; i < 4; ++i) {
        bias[i] = *(const float4*)(b2 + chb[i]);
        gv[i]   = *(const float4*)(lng + chb[i]);
        bv[i]   = *(const float4*)(lnb + chb[i]);
    }
#pragma unroll
    for (int j = 0; j < 2; ++j) {
#pragma unroll
        for (int i = 0; i < 4; ++i) {
            ushort4 r4 = *(const ushort4*)(X + (size_t)arow[j] * 128 + chb[i]);
            acc2[i][j][0] += ((const float*)&bias[i])[0] + bf2f(r4.x);
            acc2[i][j][1] += ((const float*)&bias[i])[1] + bf2f(r4.y);
            acc2[i][j][2] += ((const float*)&bias[i])[2] + bf2f(r4.z);
            acc2[i][j][3] += ((const float*)&bias[i])[3] + bf2f(r4.w);
        }
    }
#pragma unroll
    for (int j = 0; j < 2; ++j) {
        float s = 0.f, q = 0.f;
#pragma unroll
        for (int i = 0; i < 4; ++i)
#pragma unroll
            for (int reg = 0; reg < 4; ++reg) {
                float v = acc2[i][j][reg];
                s += v; q += v * v;
            }
        s += __shfl_xor(s, 16); q += __shfl_xor(q, 16);
        s += __shfl_xor(s, 32); q += __shfl_xor(q, 32);
        if (lq == 0) lnS[chh][rh * 32 + j * 16 + lr] = make_float2(s, q);
    }
    __syncthreads();
#pragma unroll
    for (int j = 0; j < 2; ++j) {
        int rl = rh * 32 + j * 16 + lr;
        float2 s0 = lnS[0][rl], s1 = lnS[1][rl];
        float mu  = (s0.x + s1.x) * (1.0f / 128.0f);
        float var = (s0.y + s1.y) * (1.0f / 128.0f) - mu * mu;
        float rstd = rsqrtf(var + 1e-5f);
#pragma unroll
        for (int i = 0; i < 4; ++i) {
            uint2 u;
            u.x = pkbf((acc2[i][j][0] - mu) * rstd * ((const float*)&gv[i])[0] + ((const float*)&bv[i])[0],
                       (acc2[i][j][1] - mu) * rstd * ((const float*)&gv[i])[1] + ((const float*)&bv[i])[1]);
            u.y = pkbf((acc2[i][j][2] - mu) * rstd * ((const float*)&gv[i])[2] + ((const float*)&bv[i])[2],
                       (acc2[i][j][3] - mu) * rstd * ((const float*)&gv[i])[3] + ((const float*)&bv[i])[3]);
            *(uint2*)(Out + (size_t)arow[j] * 128 + chb[i]) = u;
        }
    }
}

// ---------------------------------------------------------------------------
__global__ void gather_kernel(const ushort* __restrict__ x,
                              const int* __restrict__ seqlen,
                              float* __restrict__ out, int b0, int Bc)
{
    int i = blockIdx.x * 256 + threadIdx.x;
    if (i >= Bc * D) return;
    int b = i >> 7, d = i & 127;
    int idx = seqlen[b0 + b] - 1;
    out[(size_t)(b0 + b) * D + d] = bf2f(x[((size_t)b * SEQ + idx) * D + d]);
}

// ---------------------------------------------------------------------------
extern "C" void kernel_launch(void* const* d_in, const int* in_sizes, int n_in,
                              void* d_out, int out_size, void* d_ws, size_t ws_size,
                              hipStream_t stream)
{
    const float* token_emb  = (const float*)d_in[0];
    const float* emb_ln_g   = (const float*)d_in[1];
    const float* emb_ln_b   = (const float*)d_in[2];
    const float* params_log = (const float*)d_in[3];
    const float* in_wr      = (const float*)d_in[4];
    const float* in_wi      = (const float*)d_in[5];
    const float* in_br      = (const float*)d_in[6];
    const float* in_bi      = (const float*)d_in[7];
    const float* out_wr     = (const float*)d_in[8];
    const float* out_wi     = (const float*)d_in[9];
    const float* out_br     = (const float*)d_in[10];
    const float* lru_ln_g   = (const float*)d_in[12];
    const float* lru_ln_b   = (const float*)d_in[13];
    const float* w1         = (const float*)d_in[14];
    const float* b1         = (const float*)d_in[15];
    const float* w2         = (const float*)d_in[16];
    const float* b2         = (const float*)d_in[17];
    const float* ffn_ln_g   = (const float*)d_in[18];
    const float* ffn_ln_b   = (const float*)d_in[19];
    const int*   item_seq   = (const int*)d_in[20];
    const int*   item_seq_len = (const int*)d_in[21];
    float* out = (float*)d_out;

    char* ws = (char*)d_ws;
    ushort* Winb   = (ushort*)ws;                      ws += NLAY * 65536 * 2;
    ushort* W2effb = (ushort*)ws;                      ws += NLAY * 65536 * 2;
    ushort* w1b    = (ushort*)ws;                      ws += NLAY * 65536 * 2;
    ushort* w2b    = (ushort*)ws;                      ws += NLAY * 65536 * 2;
    float* lam_pow = (float*)ws;                       ws += NLAY * 65536 * 4;
    float* scale_in = (float*)ws;                      ws += NLAY * 512 * 4;
    float* bias_in  = (float*)ws;                      ws += NLAY * 512 * 4;
    size_t table_bytes = (size_t)(ws - (char*)d_ws);

    int Bc = B_TOT;
    while (Bc > 32) {
        size_t need = table_bytes + (size_t)Bc * SEQ * (D * 2 + 2 * DH * 2) + 1024;
        if (need <= ws_size) break;
        Bc >>= 1;
    }
    ushort* xb = (ushort*)ws;                          ws += (size_t)Bc * SEQ * D * 2;
    ushort* hb = (ushort*)ws;

    setup_params_kernel<<<NLAY, 256, 0, stream>>>(params_log, in_br, in_bi,
                                                  lam_pow, scale_in, bias_in);
    setup_weights_kernel<<<NLAY * 65536 / 256, 256, 0, stream>>>(
        in_wr, in_wi, out_wr, out_wi, w1, w2, Winb, W2effb, w1b, w2b);

    for (int b0 = 0; b0 < B_TOT; b0 += Bc) {
        int M = Bc * SEQ;
        embed_ln_kernel<<<M / 4, 256, 0, stream>>>(
            token_emb, item_seq + (size_t)b0 * SEQ, emb_ln_g, emb_ln_b, xb);

        for (int li = 0; li < NLAY; ++li) {
            // in-proj -> H layout
            gemm_bf16_kernel<0, false><<<dim3(M / 128, 4), 256, 0, stream>>>(
                xb, Winb + (size_t)li * 65536, hb, M, 2 * DH, D,
                scale_in + li * 512, bias_in + li * 512,
                (const ushort*)0, (const float*)0, (const float*)0);
            // exact tree scan (in place, H layout, register-resident)
            lru_scan_kernel<<<dim3(16, Bc), 512, 0, stream>>>(
                hb, (const float2*)(lam_pow + (size_t)li * 65536),
                item_seq + (size_t)b0 * SEQ);
            // out-proj + bias + residual + LN -> bf16 x
            gemm_bf16_kernel<1, true><<<dim3(M / 128, 1), 256, 0, stream>>>(
                hb, W2effb + (size_t)li * 65536, xb, M, D, 2 * DH,
                out_br + li * D, (const float*)0, xb,
                lru_ln_g + li * D, lru_ln_b + li * D);
            // fused FFN1+gelu+FFN2+residual+LN (in place on xb)
            ffn_fused_kernel<<<dim3(M / 64), 256, 0, stream>>>(
                xb, w1b + (size_t)li * 65536, w2b + (size_t)li * 65536, xb,
                b1 + li * DFF, b2 + li * D,
                ffn_ln_g + li * D, ffn_ln_b + li * D);
        }
        gather_kernel<<<(Bc * D + 255) / 256, 256, 0, stream>>>(
            xb, item_seq_len, out, b0, Bc);
    }
}